// Round 1
// baseline (612.086 us; speedup 1.0000x reference)
//
#include <hip/hip_runtime.h>
#include <hip/hip_bf16.h>
#include <stdint.h>

// Problem constants: B=4, S=4096, D=1024, H=16, HD=64, LK=256
typedef __bf16 bf16_t;
typedef __attribute__((ext_vector_type(8))) __bf16 bf16x8;
typedef __attribute__((ext_vector_type(4))) __bf16 bf16x4;
typedef __attribute__((ext_vector_type(4))) float f32x4;

#define TO_GLB(p) ((const __attribute__((address_space(1))) void*)(p))
#define TO_LDS(p) ((__attribute__((address_space(3))) void*)(p))

// ---------------- cast fp32 -> bf16 (vectorized) ----------------
__global__ __launch_bounds__(256) void cast_bf16_kernel(const float* __restrict__ src,
                                                        bf16_t* __restrict__ dst, int n4) {
  int i = blockIdx.x * 256 + threadIdx.x;
  if (i < n4) {
    float4 v = ((const float4*)src)[i];
    bf16x4 o;
    o[0] = (bf16_t)v.x; o[1] = (bf16_t)v.y; o[2] = (bf16_t)v.z; o[3] = (bf16_t)v.w;
    ((bf16x4*)dst)[i] = o;
  }
}

// ---------------- transpose-cast weights: out[c][r] = W[r][c], bf16 ----------------
// R,C multiples of 64. Grid (C/64, R/64), 256 threads.
__global__ __launch_bounds__(256) void transpose_cast(const float* __restrict__ W,
                                                      bf16_t* __restrict__ out, int R, int C) {
  __shared__ bf16_t tile[64][72];
  int r0 = blockIdx.y * 64, c0 = blockIdx.x * 64;
  int tid = threadIdx.x;
#pragma unroll
  for (int p = 0; p < 4; ++p) {
    int r = p * 16 + (tid >> 4);
    int c = (tid & 15) * 4;
    float4 v = *(const float4*)(W + (size_t)(r0 + r) * C + c0 + c);
    tile[r][c + 0] = (bf16_t)v.x; tile[r][c + 1] = (bf16_t)v.y;
    tile[r][c + 2] = (bf16_t)v.z; tile[r][c + 3] = (bf16_t)v.w;
  }
  __syncthreads();
#pragma unroll
  for (int p = 0; p < 4; ++p) {
    int c = p * 16 + (tid >> 4);
    int r = (tid & 15) * 4;
    bf16x4 o;
    o[0] = tile[r + 0][c]; o[1] = tile[r + 1][c];
    o[2] = tile[r + 2][c]; o[3] = tile[r + 3][c];
    *(bf16x4*)(out + (size_t)(c0 + c) * R + r0 + r) = o;
  }
}

// ---------------- 128x128xBK32 bf16 GEMM, C = A @ B^T (both [row][k]) ----------------
// mode 0: QKV projection epilogue (split heads; K,V written transposed with mask+bias)
// mode 1: output projection epilogue (+bo, fp32 out)
__global__ __launch_bounds__(256) void gemm_bt_128(
    const bf16_t* __restrict__ A, const bf16_t* __restrict__ B, int K, int mode,
    const float* __restrict__ bq, const float* __restrict__ bk, const float* __restrict__ bv,
    const float* __restrict__ mask,
    bf16_t* __restrict__ Q, bf16_t* __restrict__ KT, bf16_t* __restrict__ VT,
    const float* __restrict__ bo, float* __restrict__ out) {
  int tid = threadIdx.x;
  int lane = tid & 63, wv = tid >> 6;
  int wm = wv >> 1, wn = wv & 1;
  int q = lane >> 4, m_in = lane & 15;
  size_t m0 = (size_t)blockIdx.x * 128;
  size_t n0 = (size_t)blockIdx.y * 128;
  const bf16_t* Ab = A + m0 * K;
  const bf16_t* Bb = B + n0 * K;
  __shared__ __align__(16) bf16_t As[128 * 32];
  __shared__ __align__(16) bf16_t Bs[128 * 32];

  f32x4 acc[4][4];
  f32x4 z = {0.f, 0.f, 0.f, 0.f};
#pragma unroll
  for (int mt = 0; mt < 4; ++mt)
#pragma unroll
    for (int nt = 0; nt < 4; ++nt) acc[mt][nt] = z;

  for (int k0 = 0; k0 < K; k0 += 32) {
#pragma unroll
    for (int i = 0; i < 2; ++i) {
      int ch = wv * 128 + i * 64 + lane;  // 16B chunk id; 4 chunks per 64B row
      const bf16_t* ga = Ab + (size_t)(ch >> 2) * K + k0 + (ch & 3) * 8;
      __builtin_amdgcn_global_load_lds(TO_GLB(ga), TO_LDS(As + (wv * 2 + i) * 512), 16, 0, 0);
      const bf16_t* gb = Bb + (size_t)(ch >> 2) * K + k0 + (ch & 3) * 8;
      __builtin_amdgcn_global_load_lds(TO_GLB(gb), TO_LDS(Bs + (wv * 2 + i) * 512), 16, 0, 0);
    }
    __syncthreads();
    bf16x8 af[4], bfr[4];
#pragma unroll
    for (int t = 0; t < 4; ++t)
      af[t] = *(const bf16x8*)(As + (wm * 64 + t * 16 + m_in) * 32 + q * 8);
#pragma unroll
    for (int t = 0; t < 4; ++t)
      bfr[t] = *(const bf16x8*)(Bs + (wn * 64 + t * 16 + m_in) * 32 + q * 8);
#pragma unroll
    for (int mt = 0; mt < 4; ++mt)
#pragma unroll
      for (int nt = 0; nt < 4; ++nt)
        acc[mt][nt] = __builtin_amdgcn_mfma_f32_16x16x32_bf16(af[mt], bfr[nt], acc[mt][nt], 0, 0, 0);
    __syncthreads();
  }

  if (mode == 0) {
#pragma unroll
    for (int mt = 0; mt < 4; ++mt) {
      int mbase = (int)m0 + wm * 64 + mt * 16 + q * 4;  // token index, %4==0
      int b = mbase >> 12, s = mbase & 4095;
      float mk[4];
#pragma unroll
      for (int r = 0; r < 4; ++r) mk[r] = mask[b * 4096 + s + r];
#pragma unroll
      for (int nt = 0; nt < 4; ++nt) {
        int nG = (int)n0 + wn * 64 + nt * 16 + m_in;
        int proj = nG >> 10, c = nG & 1023, h = c >> 6, hd = c & 63;
        const float* bp = (proj == 0) ? bq : ((proj == 1) ? bk : bv);
        float bias = bp[c];
        if (proj == 0) {
#pragma unroll
          for (int r = 0; r < 4; ++r)
            Q[((size_t)(b * 16 + h) * 4096 + s + r) * 64 + hd] = (bf16_t)(acc[mt][nt][r] + bias);
        } else {
          bf16_t* dst = (proj == 1) ? KT : VT;
          bf16x4 v;
#pragma unroll
          for (int r = 0; r < 4; ++r) v[r] = (bf16_t)((acc[mt][nt][r] + bias) * mk[r]);
          *(bf16x4*)(dst + ((size_t)(b * 16 + h) * 64 + hd) * 4096 + s) = v;
        }
      }
    }
  } else {
#pragma unroll
    for (int mt = 0; mt < 4; ++mt) {
      int t = (int)m0 + wm * 64 + mt * 16 + q * 4;
#pragma unroll
      for (int nt = 0; nt < 4; ++nt) {
        int nG = (int)n0 + wn * 64 + nt * 16 + m_in;
        float bias = bo[nG];
#pragma unroll
        for (int r = 0; r < 4; ++r) out[(size_t)(t + r) * 1024 + nG] = acc[mt][nt][r] + bias;
      }
    }
  }
}

// ---------------- GEMM2: Kp/Vp = E_h @ (masked K/V)^T, per (b,h) ----------------
// Tile M=128(lk) x N=64(hd), BK=64. Grid (2, 64, 2): x=mtile, y=bh, z=kv.
// kv=0 -> Kp natural [lk][hd]; kv=1 -> Vp transposed [hd][lk].
__global__ __launch_bounds__(256) void gemm2_kernel(
    const bf16_t* __restrict__ E, const bf16_t* __restrict__ KT, const bf16_t* __restrict__ VT,
    bf16_t* __restrict__ Kp, bf16_t* __restrict__ VpT) {
  int tid = threadIdx.x, lane = tid & 63, wv = tid >> 6;
  int q = lane >> 4, m_in = lane & 15;
  int mt0 = blockIdx.x;
  int bh = blockIdx.y;
  int kv = blockIdx.z;
  int h = bh & 15;
  const bf16_t* Ab = E + (size_t)h * 256 * 4096 + (size_t)mt0 * 128 * 4096;
  const bf16_t* Bb = (kv ? VT : KT) + (size_t)bh * 64 * 4096;
  __shared__ __align__(16) bf16_t As[128 * 64];
  __shared__ __align__(16) bf16_t Bs[64 * 64];

  f32x4 acc[2][4];
  f32x4 z = {0.f, 0.f, 0.f, 0.f};
#pragma unroll
  for (int mt = 0; mt < 2; ++mt)
#pragma unroll
    for (int nt = 0; nt < 4; ++nt) acc[mt][nt] = z;

  for (int k0 = 0; k0 < 4096; k0 += 64) {
#pragma unroll
    for (int it = 0; it < 4; ++it) {  // A: 1024 chunks of 16B; 8 chunks per 128B row
      int ch = it * 256 + wv * 64 + lane;
      const bf16_t* ga = Ab + (size_t)(ch >> 3) * 4096 + k0 + (ch & 7) * 8;
      __builtin_amdgcn_global_load_lds(TO_GLB(ga), TO_LDS(As + (it * 256 + wv * 64) * 8), 16, 0, 0);
    }
#pragma unroll
    for (int it = 0; it < 2; ++it) {  // B: 512 chunks
      int ch = it * 256 + wv * 64 + lane;
      const bf16_t* gb = Bb + (size_t)(ch >> 3) * 4096 + k0 + (ch & 7) * 8;
      __builtin_amdgcn_global_load_lds(TO_GLB(gb), TO_LDS(Bs + (it * 256 + wv * 64) * 8), 16, 0, 0);
    }
    __syncthreads();
#pragma unroll
    for (int kk = 0; kk < 2; ++kk) {
      bf16x8 af[2], bfr[4];
#pragma unroll
      for (int mt = 0; mt < 2; ++mt)
        af[mt] = *(const bf16x8*)(As + (wv * 32 + mt * 16 + m_in) * 64 + kk * 32 + q * 8);
#pragma unroll
      for (int nt = 0; nt < 4; ++nt)
        bfr[nt] = *(const bf16x8*)(Bs + (nt * 16 + m_in) * 64 + kk * 32 + q * 8);
#pragma unroll
      for (int mt = 0; mt < 2; ++mt)
#pragma unroll
        for (int nt = 0; nt < 4; ++nt)
          acc[mt][nt] = __builtin_amdgcn_mfma_f32_16x16x32_bf16(af[mt], bfr[nt], acc[mt][nt], 0, 0, 0);
    }
    __syncthreads();
  }

#pragma unroll
  for (int mt = 0; mt < 2; ++mt) {
    int lk = mt0 * 128 + wv * 32 + mt * 16 + q * 4;
#pragma unroll
    for (int nt = 0; nt < 4; ++nt) {
      int hd = nt * 16 + m_in;
      if (kv == 0) {
#pragma unroll
        for (int r = 0; r < 4; ++r)
          Kp[(size_t)bh * 256 * 64 + (size_t)(lk + r) * 64 + hd] = (bf16_t)acc[mt][nt][r];
      } else {
        bf16x4 v;
#pragma unroll
        for (int r = 0; r < 4; ++r) v[r] = (bf16_t)acc[mt][nt][r];
        *(bf16x4*)(VpT + (size_t)bh * 64 * 256 + (size_t)hd * 256 + lk) = v;
      }
    }
  }
}

// ---------------- fused attention: scores -> softmax -> PV ----------------
// Grid (S/64, B*H), 256 threads (4 waves x 16 Q-rows each).
__global__ __launch_bounds__(256) void attn_kernel(
    const bf16_t* __restrict__ Q, const bf16_t* __restrict__ Kp, const bf16_t* __restrict__ VpT,
    bf16_t* __restrict__ Xo) {
  int tid = threadIdx.x, lane = tid & 63, wv = tid >> 6;
  int q = lane >> 4, m_in = lane & 15;
  int s0 = blockIdx.x * 64;
  int bh = blockIdx.y;
  int b = bh >> 4, h = bh & 15;
  const bf16_t* Qb = Q + ((size_t)bh * 4096 + s0 + wv * 16) * 64;
  const bf16_t* Kpb = Kp + (size_t)bh * 256 * 64;
  const bf16_t* Vb = VpT + (size_t)bh * 64 * 256;
  __shared__ __align__(16) bf16_t P[4][16][264];  // per-wave 16x256 P, +8 pad (2-way-free banks)

  bf16x8 aq[2];
#pragma unroll
  for (int ks = 0; ks < 2; ++ks) aq[ks] = *(const bf16x8*)(Qb + (size_t)m_in * 64 + ks * 32 + q * 8);

  f32x4 sc[16];
  f32x4 z = {0.f, 0.f, 0.f, 0.f};
#pragma unroll
  for (int nt = 0; nt < 16; ++nt) sc[nt] = z;
#pragma unroll
  for (int nt = 0; nt < 16; ++nt)
#pragma unroll
    for (int ks = 0; ks < 2; ++ks) {
      bf16x8 kb = *(const bf16x8*)(Kpb + (size_t)(nt * 16 + m_in) * 64 + ks * 32 + q * 8);
      sc[nt] = __builtin_amdgcn_mfma_f32_16x16x32_bf16(aq[ks], kb, sc[nt], 0, 0, 0);
    }

  // softmax over 256 (16 frag-cols per lane x 16 lanes in quad-group)
  float mx[4], sm[4];
#pragma unroll
  for (int r = 0; r < 4; ++r) mx[r] = -1e30f;
#pragma unroll
  for (int nt = 0; nt < 16; ++nt)
#pragma unroll
    for (int r = 0; r < 4; ++r) {
      float t = sc[nt][r] * 0.125f;  // 1/sqrt(HD)
      sc[nt][r] = t;
      mx[r] = fmaxf(mx[r], t);
    }
#pragma unroll
  for (int off = 1; off < 16; off <<= 1)
#pragma unroll
    for (int r = 0; r < 4; ++r) mx[r] = fmaxf(mx[r], __shfl_xor(mx[r], off));
#pragma unroll
  for (int r = 0; r < 4; ++r) sm[r] = 0.f;
#pragma unroll
  for (int nt = 0; nt < 16; ++nt)
#pragma unroll
    for (int r = 0; r < 4; ++r) {
      float e = __expf(sc[nt][r] - mx[r]);
      sc[nt][r] = e;
      sm[r] += e;
    }
#pragma unroll
  for (int off = 1; off < 16; off <<= 1)
#pragma unroll
    for (int r = 0; r < 4; ++r) sm[r] += __shfl_xor(sm[r], off);
  float inv[4];
#pragma unroll
  for (int r = 0; r < 4; ++r) inv[r] = 1.0f / sm[r];

#pragma unroll
  for (int nt = 0; nt < 16; ++nt)
#pragma unroll
    for (int r = 0; r < 4; ++r)
      P[wv][q * 4 + r][nt * 16 + m_in] = (bf16_t)(sc[nt][r] * inv[r]);
  __syncthreads();

  // PV: (16x256) @ (256x64); A = P from LDS, B = VpT rows (hd-major) from global
  bf16x8 pa[8];
#pragma unroll
  for (int ks = 0; ks < 8; ++ks) pa[ks] = *(const bf16x8*)(&P[wv][m_in][ks * 32 + q * 8]);
  f32x4 o[4];
#pragma unroll
  for (int nt = 0; nt < 4; ++nt) o[nt] = z;
#pragma unroll
  for (int nt = 0; nt < 4; ++nt)
#pragma unroll
    for (int ks = 0; ks < 8; ++ks) {
      bf16x8 vb = *(const bf16x8*)(Vb + (size_t)(nt * 16 + m_in) * 256 + ks * 32 + q * 8);
      o[nt] = __builtin_amdgcn_mfma_f32_16x16x32_bf16(pa[ks], vb, o[nt], 0, 0, 0);
    }

#pragma unroll
  for (int nt = 0; nt < 4; ++nt)
#pragma unroll
    for (int r = 0; r < 4; ++r)
      Xo[((size_t)b * 4096 + s0 + wv * 16 + q * 4 + r) * 1024 + h * 64 + nt * 16 + m_in] =
          (bf16_t)o[nt][r];
}

extern "C" void kernel_launch(void* const* d_in, const int* in_sizes, int n_in,
                              void* d_out, int out_size, void* d_ws, size_t ws_size,
                              hipStream_t stream) {
  const float* X = (const float*)d_in[0];
  const float* mask = (const float*)d_in[1];
  const float* Wq = (const float*)d_in[2];
  const float* bq = (const float*)d_in[3];
  const float* Wk = (const float*)d_in[4];
  const float* bk = (const float*)d_in[5];
  const float* Wv = (const float*)d_in[6];
  const float* bv = (const float*)d_in[7];
  const float* E = (const float*)d_in[8];
  const float* Wo = (const float*)d_in[9];
  const float* bo = (const float*)d_in[10];
  float* out = (float*)d_out;

  char* ws = (char*)d_ws;
  const size_t SZ = 33554432;  // 16M bf16 elements
  bf16_t* Xb = (bf16_t*)(ws);              // reused as Xo after gemm1
  bf16_t* Eb = (bf16_t*)(ws + SZ);
  bf16_t* Qb = (bf16_t*)(ws + 2 * SZ);
  bf16_t* KT = (bf16_t*)(ws + 3 * SZ);     // (B,H,HD,S) masked
  bf16_t* VT = (bf16_t*)(ws + 4 * SZ);     // (B,H,HD,S) masked
  bf16_t* Kp = (bf16_t*)(ws + 5 * SZ);                 // (B,H,LK,HD)
  bf16_t* VpT = (bf16_t*)(ws + 5 * SZ + 8388608);      // (B,H,HD,LK)
  bf16_t* WqkvT = (bf16_t*)(ws + 5 * SZ + 2 * 8388608);           // (3072,1024)
  bf16_t* WoT = (bf16_t*)(ws + 5 * SZ + 2 * 8388608 + 6291456);   // (1024,1024)
  bf16_t* Xo = Xb;

  cast_bf16_kernel<<<16384, 256, 0, stream>>>(X, Xb, 4194304);
  cast_bf16_kernel<<<16384, 256, 0, stream>>>(E, Eb, 4194304);
  dim3 tg(16, 16);
  transpose_cast<<<tg, 256, 0, stream>>>(Wq, WqkvT, 1024, 1024);
  transpose_cast<<<tg, 256, 0, stream>>>(Wk, WqkvT + 1048576, 1024, 1024);
  transpose_cast<<<tg, 256, 0, stream>>>(Wv, WqkvT + 2097152, 1024, 1024);
  transpose_cast<<<tg, 256, 0, stream>>>(Wo, WoT, 1024, 1024);

  gemm_bt_128<<<dim3(128, 24), 256, 0, stream>>>(Xb, WqkvT, 1024, 0, bq, bk, bv, mask,
                                                 Qb, KT, VT, nullptr, nullptr);
  gemm2_kernel<<<dim3(2, 64, 2), 256, 0, stream>>>(Eb, KT, VT, Kp, VpT);
  attn_kernel<<<dim3(64, 64), 256, 0, stream>>>(Qb, Kp, VpT, Xo);
  gemm_bt_128<<<dim3(128, 8), 256, 0, stream>>>(Xo, WoT, 1024, 1, nullptr, nullptr, nullptr,
                                                nullptr, nullptr, nullptr, nullptr, bo, out);
}

// Round 2
// 521.549 us; speedup vs baseline: 1.1736x; 1.1736x over previous
//
#include <hip/hip_runtime.h>
#include <hip/hip_bf16.h>
#include <stdint.h>

// Problem constants: B=4, S=4096, D=1024, H=16, HD=64, LK=256
typedef __bf16 bf16_t;
typedef __attribute__((ext_vector_type(8))) __bf16 bf16x8;
typedef __attribute__((ext_vector_type(4))) __bf16 bf16x4;
typedef __attribute__((ext_vector_type(4))) float f32x4;

#define TO_GLB(p) ((const __attribute__((address_space(1))) void*)(p))
#define TO_LDS(p) ((__attribute__((address_space(3))) void*)(p))

// ---------------- cast fp32 -> bf16 (vectorized) ----------------
__global__ __launch_bounds__(256) void cast_bf16_kernel(const float* __restrict__ src,
                                                        bf16_t* __restrict__ dst, int n4) {
  int i = blockIdx.x * 256 + threadIdx.x;
  if (i < n4) {
    float4 v = ((const float4*)src)[i];
    bf16x4 o;
    o[0] = (bf16_t)v.x; o[1] = (bf16_t)v.y; o[2] = (bf16_t)v.z; o[3] = (bf16_t)v.w;
    ((bf16x4*)dst)[i] = o;
  }
}

// ---------------- transpose-cast weights: out[c][r] = W[r][c], bf16 ----------------
__global__ __launch_bounds__(256) void transpose_cast(const float* __restrict__ W,
                                                      bf16_t* __restrict__ out, int R, int C) {
  __shared__ bf16_t tile[64][72];
  int r0 = blockIdx.y * 64, c0 = blockIdx.x * 64;
  int tid = threadIdx.x;
#pragma unroll
  for (int p = 0; p < 4; ++p) {
    int r = p * 16 + (tid >> 4);
    int c = (tid & 15) * 4;
    float4 v = *(const float4*)(W + (size_t)(r0 + r) * C + c0 + c);
    tile[r][c + 0] = (bf16_t)v.x; tile[r][c + 1] = (bf16_t)v.y;
    tile[r][c + 2] = (bf16_t)v.z; tile[r][c + 3] = (bf16_t)v.w;
  }
  __syncthreads();
#pragma unroll
  for (int p = 0; p < 4; ++p) {
    int c = p * 16 + (tid >> 4);
    int r = (tid & 15) * 4;
    bf16x4 o;
    o[0] = tile[r + 0][c]; o[1] = tile[r + 1][c];
    o[2] = tile[r + 2][c]; o[3] = tile[r + 3][c];
    *(bf16x4*)(out + (size_t)(c0 + c) * R + r0 + r) = o;
  }
}

// ---------------- 128x128xBK32 bf16 GEMM, C = A @ B^T (both [row][k]) ----------------
// mode 0: QKV projection epilogue; mode 1: output projection epilogue (+bo, fp32)
__global__ __launch_bounds__(256) void gemm_bt_128(
    const bf16_t* __restrict__ A, const bf16_t* __restrict__ B, int K, int mode,
    const float* __restrict__ bq, const float* __restrict__ bk, const float* __restrict__ bv,
    const float* __restrict__ mask,
    bf16_t* __restrict__ Q, bf16_t* __restrict__ KT, bf16_t* __restrict__ VT,
    const float* __restrict__ bo, float* __restrict__ out) {
  int tid = threadIdx.x;
  int lane = tid & 63, wv = tid >> 6;
  int wm = wv >> 1, wn = wv & 1;
  int q = lane >> 4, m_in = lane & 15;
  size_t m0 = (size_t)blockIdx.x * 128;
  size_t n0 = (size_t)blockIdx.y * 128;
  const bf16_t* Ab = A + m0 * K;
  const bf16_t* Bb = B + n0 * K;
  __shared__ __align__(16) bf16_t As[128 * 32];
  __shared__ __align__(16) bf16_t Bs[128 * 32];

  f32x4 acc[4][4];
  f32x4 z = {0.f, 0.f, 0.f, 0.f};
#pragma unroll
  for (int mt = 0; mt < 4; ++mt)
#pragma unroll
    for (int nt = 0; nt < 4; ++nt) acc[mt][nt] = z;

  for (int k0 = 0; k0 < K; k0 += 32) {
#pragma unroll
    for (int i = 0; i < 2; ++i) {
      int ch = wv * 128 + i * 64 + lane;  // 16B chunk id; 4 chunks per 64B row
      const bf16_t* ga = Ab + (size_t)(ch >> 2) * K + k0 + (ch & 3) * 8;
      __builtin_amdgcn_global_load_lds(TO_GLB(ga), TO_LDS(As + (wv * 2 + i) * 512), 16, 0, 0);
      const bf16_t* gb = Bb + (size_t)(ch >> 2) * K + k0 + (ch & 3) * 8;
      __builtin_amdgcn_global_load_lds(TO_GLB(gb), TO_LDS(Bs + (wv * 2 + i) * 512), 16, 0, 0);
    }
    __syncthreads();
    bf16x8 af[4], bfr[4];
#pragma unroll
    for (int t = 0; t < 4; ++t)
      af[t] = *(const bf16x8*)(As + (wm * 64 + t * 16 + m_in) * 32 + q * 8);
#pragma unroll
    for (int t = 0; t < 4; ++t)
      bfr[t] = *(const bf16x8*)(Bs + (wn * 64 + t * 16 + m_in) * 32 + q * 8);
#pragma unroll
    for (int mt = 0; mt < 4; ++mt)
#pragma unroll
      for (int nt = 0; nt < 4; ++nt)
        acc[mt][nt] = __builtin_amdgcn_mfma_f32_16x16x32_bf16(af[mt], bfr[nt], acc[mt][nt], 0, 0, 0);
    __syncthreads();
  }

  if (mode == 0) {
#pragma unroll
    for (int mt = 0; mt < 4; ++mt) {
      int mbase = (int)m0 + wm * 64 + mt * 16 + q * 4;  // token index, %4==0
      int b = mbase >> 12, s = mbase & 4095;
      float mk[4];
#pragma unroll
      for (int r = 0; r < 4; ++r) mk[r] = mask[b * 4096 + s + r];
#pragma unroll
      for (int nt = 0; nt < 4; ++nt) {
        int nG = (int)n0 + wn * 64 + nt * 16 + m_in;
        int proj = nG >> 10, c = nG & 1023, h = c >> 6, hd = c & 63;
        const float* bp = (proj == 0) ? bq : ((proj == 1) ? bk : bv);
        float bias = bp[c];
        if (proj == 0) {
#pragma unroll
          for (int r = 0; r < 4; ++r)
            Q[((size_t)(b * 16 + h) * 4096 + s + r) * 64 + hd] = (bf16_t)(acc[mt][nt][r] + bias);
        } else {
          bf16_t* dst = (proj == 1) ? KT : VT;
          bf16x4 v;
#pragma unroll
          for (int r = 0; r < 4; ++r) v[r] = (bf16_t)((acc[mt][nt][r] + bias) * mk[r]);
          *(bf16x4*)(dst + ((size_t)(b * 16 + h) * 64 + hd) * 4096 + s) = v;
        }
      }
    }
  } else {
#pragma unroll
    for (int mt = 0; mt < 4; ++mt) {
      int t = (int)m0 + wm * 64 + mt * 16 + q * 4;
#pragma unroll
      for (int nt = 0; nt < 4; ++nt) {
        int nG = (int)n0 + wn * 64 + nt * 16 + m_in;
        float bias = bo[nG];
#pragma unroll
        for (int r = 0; r < 4; ++r) out[(size_t)(t + r) * 1024 + nG] = acc[mt][nt][r] + bias;
      }
    }
  }
}

// ---------------- GEMM2: Kp/Vp = E_h @ (masked K/V)^T, per (b,h) ----------------
// 512 threads (8 waves), tile M=128(lk) x N=64(hd), BK=128. Grid (2, 64, 2).
// LDS sub-tiled [kk][row][32] so global_load_lds stays contiguous while frag
// reads get 64B-row stride (no 16-way conflicts).
// kv=0 -> Kp natural [lk][hd]; kv=1 -> Vp transposed [hd][lk].
__global__ __launch_bounds__(512) void gemm2_kernel(
    const bf16_t* __restrict__ E, const bf16_t* __restrict__ KT, const bf16_t* __restrict__ VT,
    bf16_t* __restrict__ Kp, bf16_t* __restrict__ VpT) {
  int tid = threadIdx.x, lane = tid & 63, wv = tid >> 6;  // 8 waves
  int wm = wv >> 1, wn = wv & 1;
  int q = lane >> 4, m_in = lane & 15;
  int mt0 = blockIdx.x;
  int bh = blockIdx.y;
  int kv = blockIdx.z;
  int h = bh & 15;
  const bf16_t* Ab = E + (size_t)h * 256 * 4096 + (size_t)mt0 * 128 * 4096;
  const bf16_t* Bb = (kv ? VT : KT) + (size_t)bh * 64 * 4096;
  __shared__ __align__(16) bf16_t As[4 * 128 * 32];  // 32KB, [sub][row][32]
  __shared__ __align__(16) bf16_t Bs[4 * 64 * 32];   // 16KB, [sub][row][32]

  f32x4 acc[2][2];
  f32x4 z = {0.f, 0.f, 0.f, 0.f};
#pragma unroll
  for (int mt = 0; mt < 2; ++mt)
#pragma unroll
    for (int nt = 0; nt < 2; ++nt) acc[mt][nt] = z;

  for (int k0 = 0; k0 < 4096; k0 += 128) {
#pragma unroll
    for (int it = 0; it < 4; ++it) {  // As: 2048 chunks of 16B
      int l = it * 512 + tid;
      int sub = l >> 9, row = (l >> 2) & 127, cc = l & 3;
      const bf16_t* ga = Ab + (size_t)row * 4096 + k0 + sub * 32 + cc * 8;
      __builtin_amdgcn_global_load_lds(TO_GLB(ga), TO_LDS(As + (it * 512 + wv * 64) * 8), 16, 0, 0);
    }
#pragma unroll
    for (int it = 0; it < 2; ++it) {  // Bs: 1024 chunks
      int l = it * 512 + tid;
      int sub = l >> 8, row = (l >> 2) & 63, cc = l & 3;
      const bf16_t* gb = Bb + (size_t)row * 4096 + k0 + sub * 32 + cc * 8;
      __builtin_amdgcn_global_load_lds(TO_GLB(gb), TO_LDS(Bs + (it * 512 + wv * 64) * 8), 16, 0, 0);
    }
    __syncthreads();
#pragma unroll
    for (int kk = 0; kk < 4; ++kk) {
      bf16x8 af[2], bfr[2];
#pragma unroll
      for (int mt = 0; mt < 2; ++mt)
        af[mt] = *(const bf16x8*)(As + kk * 4096 + (wm * 32 + mt * 16 + m_in) * 32 + q * 8);
#pragma unroll
      for (int nt = 0; nt < 2; ++nt)
        bfr[nt] = *(const bf16x8*)(Bs + kk * 2048 + (wn * 32 + nt * 16 + m_in) * 32 + q * 8);
#pragma unroll
      for (int mt = 0; mt < 2; ++mt)
#pragma unroll
        for (int nt = 0; nt < 2; ++nt)
          acc[mt][nt] = __builtin_amdgcn_mfma_f32_16x16x32_bf16(af[mt], bfr[nt], acc[mt][nt], 0, 0, 0);
    }
    __syncthreads();
  }

#pragma unroll
  for (int mt = 0; mt < 2; ++mt) {
    int lk = mt0 * 128 + wm * 32 + mt * 16 + q * 4;
#pragma unroll
    for (int nt = 0; nt < 2; ++nt) {
      int hd = wn * 32 + nt * 16 + m_in;
      if (kv == 0) {
#pragma unroll
        for (int r = 0; r < 4; ++r)
          Kp[(size_t)bh * 16384 + (size_t)(lk + r) * 64 + hd] = (bf16_t)acc[mt][nt][r];
      } else {
        bf16x4 v;
#pragma unroll
        for (int r = 0; r < 4; ++r) v[r] = (bf16_t)acc[mt][nt][r];
        *(bf16x4*)(VpT + (size_t)bh * 16384 + (size_t)hd * 256 + lk) = v;
      }
    }
  }
}

// ---------------- fused attention: scores -> softmax -> PV ----------------
// Grid (S/64, B*H), 256 threads (4 waves x 16 Q-rows each).
// One 32KB LDS buffer staged 3x: Kp (sub-tiled) -> P (xor-swizzled) -> Vp (sub-tiled).
__global__ __launch_bounds__(256) void attn_kernel(
    const bf16_t* __restrict__ Q, const bf16_t* __restrict__ Kp, const bf16_t* __restrict__ VpT,
    bf16_t* __restrict__ Xo) {
  int tid = threadIdx.x, lane = tid & 63, wv = tid >> 6;
  int q = lane >> 4, m_in = lane & 15;
  int s0 = blockIdx.x * 64;
  int bh = blockIdx.y;
  int b = bh >> 4, h = bh & 15;
  const bf16_t* Qb = Q + ((size_t)bh * 4096 + s0 + wv * 16) * 64;
  const bf16_t* Kpb = Kp + (size_t)bh * 16384;
  const bf16_t* Vb = VpT + (size_t)bh * 16384;
  __shared__ __align__(16) bf16_t buf[16384];  // 32KB, reused Kp -> P -> Vp

  // stage Kp [256][64] as sub-tiled [2][256][32]
#pragma unroll
  for (int it = 0; it < 8; ++it) {
    int l = it * 256 + tid;
    int sub = l >> 10, row = (l >> 2) & 255, cc = l & 3;
    const bf16_t* g = Kpb + row * 64 + sub * 32 + cc * 8;
    __builtin_amdgcn_global_load_lds(TO_GLB(g), TO_LDS(buf + (it * 256 + wv * 64) * 8), 16, 0, 0);
  }
  bf16x8 aq[2];
#pragma unroll
  for (int ks = 0; ks < 2; ++ks) aq[ks] = *(const bf16x8*)(Qb + (size_t)m_in * 64 + ks * 32 + q * 8);
  __syncthreads();  // B0: Kp staged

  f32x4 sc[16];
  f32x4 z = {0.f, 0.f, 0.f, 0.f};
#pragma unroll
  for (int nt = 0; nt < 16; ++nt) sc[nt] = z;
#pragma unroll
  for (int nt = 0; nt < 16; ++nt)
#pragma unroll
    for (int ks = 0; ks < 2; ++ks) {
      bf16x8 kb = *(const bf16x8*)(buf + ks * 8192 + (nt * 16 + m_in) * 32 + q * 8);
      sc[nt] = __builtin_amdgcn_mfma_f32_16x16x32_bf16(aq[ks], kb, sc[nt], 0, 0, 0);
    }

  // softmax over 256 (per-row: 16 frag regs x 16 lanes in quad-group)
  float mx[4], sm[4];
#pragma unroll
  for (int r = 0; r < 4; ++r) mx[r] = -1e30f;
#pragma unroll
  for (int nt = 0; nt < 16; ++nt)
#pragma unroll
    for (int r = 0; r < 4; ++r) {
      float t = sc[nt][r] * 0.125f;  // 1/sqrt(HD)
      sc[nt][r] = t;
      mx[r] = fmaxf(mx[r], t);
    }
#pragma unroll
  for (int off = 1; off < 16; off <<= 1)
#pragma unroll
    for (int r = 0; r < 4; ++r) mx[r] = fmaxf(mx[r], __shfl_xor(mx[r], off));
#pragma unroll
  for (int r = 0; r < 4; ++r) sm[r] = 0.f;
#pragma unroll
  for (int nt = 0; nt < 16; ++nt)
#pragma unroll
    for (int r = 0; r < 4; ++r) {
      float e = __expf(sc[nt][r] - mx[r]);
      sc[nt][r] = e;
      sm[r] += e;
    }
#pragma unroll
  for (int off = 1; off < 16; off <<= 1)
#pragma unroll
    for (int r = 0; r < 4; ++r) sm[r] += __shfl_xor(sm[r], off);
  float inv[4];
#pragma unroll
  for (int r = 0; r < 4; ++r) inv[r] = 1.0f / sm[r];

  __syncthreads();  // B1: all waves done reading Kp; safe to overwrite buf with P

  // write P (16x256 per wave) xor-swizzled in 16B chunks: conflict-free b128 reads
  bf16_t* Pw = buf + wv * 4096;
#pragma unroll
  for (int nt = 0; nt < 16; ++nt) {
    int cw = nt * 2 + (m_in >> 3);
#pragma unroll
    for (int r = 0; r < 4; ++r) {
      int rp = q * 4 + r;
      int sw = (((cw ^ (rp & 7)) << 3) | (m_in & 7));
      Pw[rp * 256 + sw] = (bf16_t)(sc[nt][r] * inv[r]);
    }
  }
  // read own-wave A-frags (same-wave LDS dependency, no barrier needed)
  bf16x8 pa[8];
#pragma unroll
  for (int ks = 0; ks < 8; ++ks) {
    int c = ks * 4 + q;
    pa[ks] = *(const bf16x8*)(Pw + m_in * 256 + ((c ^ (m_in & 7)) << 3));
  }
  __syncthreads();  // B2: all waves have pa in regs; safe to overwrite buf with Vp

  // stage VpT [64][256] as sub-tiled [8][64][32]
#pragma unroll
  for (int it = 0; it < 8; ++it) {
    int l = it * 256 + tid;
    int sub = l >> 8, row = (l >> 2) & 63, cc = l & 3;
    const bf16_t* g = Vb + row * 256 + sub * 32 + cc * 8;
    __builtin_amdgcn_global_load_lds(TO_GLB(g), TO_LDS(buf + (it * 256 + wv * 64) * 8), 16, 0, 0);
  }
  __syncthreads();  // B3: Vp staged

  f32x4 o[4];
#pragma unroll
  for (int nt = 0; nt < 4; ++nt) o[nt] = z;
#pragma unroll
  for (int nt = 0; nt < 4; ++nt)
#pragma unroll
    for (int ks = 0; ks < 8; ++ks) {
      bf16x8 vb = *(const bf16x8*)(buf + ks * 2048 + (nt * 16 + m_in) * 32 + q * 8);
      o[nt] = __builtin_amdgcn_mfma_f32_16x16x32_bf16(pa[ks], vb, o[nt], 0, 0, 0);
    }

#pragma unroll
  for (int nt = 0; nt < 4; ++nt)
#pragma unroll
    for (int r = 0; r < 4; ++r)
      Xo[((size_t)b * 4096 + s0 + wv * 16 + q * 4 + r) * 1024 + h * 64 + nt * 16 + m_in] =
          (bf16_t)o[nt][r];
}

extern "C" void kernel_launch(void* const* d_in, const int* in_sizes, int n_in,
                              void* d_out, int out_size, void* d_ws, size_t ws_size,
                              hipStream_t stream) {
  const float* X = (const float*)d_in[0];
  const float* mask = (const float*)d_in[1];
  const float* Wq = (const float*)d_in[2];
  const float* bq = (const float*)d_in[3];
  const float* Wk = (const float*)d_in[4];
  const float* bk = (const float*)d_in[5];
  const float* Wv = (const float*)d_in[6];
  const float* bv = (const float*)d_in[7];
  const float* E = (const float*)d_in[8];
  const float* Wo = (const float*)d_in[9];
  const float* bo = (const float*)d_in[10];
  float* out = (float*)d_out;

  char* ws = (char*)d_ws;
  const size_t SZ = 33554432;  // 16M bf16 elements
  bf16_t* Xb = (bf16_t*)(ws);              // reused as Xo after gemm1
  bf16_t* Eb = (bf16_t*)(ws + SZ);
  bf16_t* Qb = (bf16_t*)(ws + 2 * SZ);
  bf16_t* KT = (bf16_t*)(ws + 3 * SZ);     // (B,H,HD,S) masked
  bf16_t* VT = (bf16_t*)(ws + 4 * SZ);     // (B,H,HD,S) masked
  bf16_t* Kp = (bf16_t*)(ws + 5 * SZ);                 // (B,H,LK,HD)
  bf16_t* VpT = (bf16_t*)(ws + 5 * SZ + 8388608);      // (B,H,HD,LK)
  bf16_t* WqkvT = (bf16_t*)(ws + 5 * SZ + 2 * 8388608);           // (3072,1024)
  bf16_t* WoT = (bf16_t*)(ws + 5 * SZ + 2 * 8388608 + 6291456);   // (1024,1024)
  bf16_t* Xo = Xb;

  cast_bf16_kernel<<<16384, 256, 0, stream>>>(X, Xb, 4194304);
  cast_bf16_kernel<<<16384, 256, 0, stream>>>(E, Eb, 4194304);
  dim3 tg(16, 16);
  transpose_cast<<<tg, 256, 0, stream>>>(Wq, WqkvT, 1024, 1024);
  transpose_cast<<<tg, 256, 0, stream>>>(Wk, WqkvT + 1048576, 1024, 1024);
  transpose_cast<<<tg, 256, 0, stream>>>(Wv, WqkvT + 2097152, 1024, 1024);
  transpose_cast<<<tg, 256, 0, stream>>>(Wo, WoT, 1024, 1024);

  gemm_bt_128<<<dim3(128, 24), 256, 0, stream>>>(Xb, WqkvT, 1024, 0, bq, bk, bv, mask,
                                                 Qb, KT, VT, nullptr, nullptr);
  gemm2_kernel<<<dim3(2, 64, 2), 512, 0, stream>>>(Eb, KT, VT, Kp, VpT);
  attn_kernel<<<dim3(64, 64), 256, 0, stream>>>(Qb, Kp, VpT, Xo);
  gemm_bt_128<<<dim3(128, 8), 256, 0, stream>>>(Xo, WoT, 1024, 1, nullptr, nullptr, nullptr,
                                                nullptr, nullptr, nullptr, nullptr, bo, out);
}

// Round 3
// 471.661 us; speedup vs baseline: 1.2977x; 1.1058x over previous
//
#include <hip/hip_runtime.h>
#include <hip/hip_bf16.h>
#include <stdint.h>

// Problem constants: B=4, S=4096, D=1024, H=16, HD=64, LK=256
typedef __bf16 bf16_t;
typedef __attribute__((ext_vector_type(8))) __bf16 bf16x8;
typedef __attribute__((ext_vector_type(4))) __bf16 bf16x4;
typedef __attribute__((ext_vector_type(4))) float f32x4;

#define TO_GLB(p) ((const __attribute__((address_space(1))) void*)(p))
#define TO_LDS(p) ((__attribute__((address_space(3))) void*)(p))

// ---------------- cast fp32 -> bf16, two tensors in one launch ----------------
__global__ __launch_bounds__(256) void cast2_bf16_kernel(const float* __restrict__ a,
                                                         bf16_t* __restrict__ da,
                                                         const float* __restrict__ b,
                                                         bf16_t* __restrict__ db, int n4) {
  int i = blockIdx.x * 256 + threadIdx.x;
  const float* s = (i < n4) ? a : b;
  bf16_t* d = (i < n4) ? da : db;
  int j = (i < n4) ? i : i - n4;
  float4 v = ((const float4*)s)[j];
  bf16x4 o;
  o[0] = (bf16_t)v.x; o[1] = (bf16_t)v.y; o[2] = (bf16_t)v.z; o[3] = (bf16_t)v.w;
  ((bf16x4*)d)[j] = o;
}

// ---------------- transpose-cast 4 square matrices (1024x1024) in one launch ----------------
// out[c][r] = W[r][c]; z selects matrix.
__global__ __launch_bounds__(256) void transpose_cast4(
    const float* __restrict__ W0, const float* __restrict__ W1, const float* __restrict__ W2,
    const float* __restrict__ W3, bf16_t* __restrict__ o0, bf16_t* __restrict__ o1,
    bf16_t* __restrict__ o2, bf16_t* __restrict__ o3) {
  const int RC = 1024;
  __shared__ bf16_t tile[64][72];
  int z = blockIdx.z;
  const float* W = (z == 0) ? W0 : (z == 1) ? W1 : (z == 2) ? W2 : W3;
  bf16_t* out = (z == 0) ? o0 : (z == 1) ? o1 : (z == 2) ? o2 : o3;
  int r0 = blockIdx.y * 64, c0 = blockIdx.x * 64;
  int tid = threadIdx.x;
#pragma unroll
  for (int p = 0; p < 4; ++p) {
    int r = p * 16 + (tid >> 4);
    int c = (tid & 15) * 4;
    float4 v = *(const float4*)(W + (size_t)(r0 + r) * RC + c0 + c);
    tile[r][c + 0] = (bf16_t)v.x; tile[r][c + 1] = (bf16_t)v.y;
    tile[r][c + 2] = (bf16_t)v.z; tile[r][c + 3] = (bf16_t)v.w;
  }
  __syncthreads();
#pragma unroll
  for (int p = 0; p < 4; ++p) {
    int c = p * 16 + (tid >> 4);
    int r = (tid & 15) * 4;
    bf16x4 o;
    o[0] = tile[r + 0][c]; o[1] = tile[r + 1][c];
    o[2] = tile[r + 2][c]; o[3] = tile[r + 3][c];
    *(bf16x4*)(out + (size_t)(c0 + c) * RC + r0 + r) = o;
  }
}

// ---------------- 128x128xBK64 bf16 GEMM, C = A @ B^T (both [row][k]) ----------------
// LDS row-major [row][64]; 16B chunks XOR-permuted at the GLOBAL source (cc^(row&7))
// so global_load_lds dest stays lane-contiguous while frag reads are conflict-free.
// mode 0: QKV projection epilogue; mode 1: output projection epilogue (+bo, fp32)
__global__ __launch_bounds__(256) void gemm_bt_128(
    const bf16_t* __restrict__ A, const bf16_t* __restrict__ B, int K, int mode,
    const float* __restrict__ bq, const float* __restrict__ bk, const float* __restrict__ bv,
    const float* __restrict__ mask,
    bf16_t* __restrict__ Q, bf16_t* __restrict__ KT, bf16_t* __restrict__ VT,
    const float* __restrict__ bo, float* __restrict__ out) {
  int tid = threadIdx.x;
  int lane = tid & 63, wv = tid >> 6;
  int wm = wv >> 1, wn = wv & 1;
  int q = lane >> 4, m_in = lane & 15;
  size_t m0 = (size_t)blockIdx.x * 128;
  size_t n0 = (size_t)blockIdx.y * 128;
  const bf16_t* Ab = A + m0 * K;
  const bf16_t* Bb = B + n0 * K;
  __shared__ __align__(16) bf16_t As[128 * 64];  // 16KB
  __shared__ __align__(16) bf16_t Bs[128 * 64];  // 16KB

  f32x4 acc[4][4];
  f32x4 z = {0.f, 0.f, 0.f, 0.f};
#pragma unroll
  for (int mt = 0; mt < 4; ++mt)
#pragma unroll
    for (int nt = 0; nt < 4; ++nt) acc[mt][nt] = z;

  for (int k0 = 0; k0 < K; k0 += 64) {
#pragma unroll
    for (int it = 0; it < 4; ++it) {  // 1024 chunks of 16B per matrix
      int l = it * 256 + tid;
      int row = l >> 3, cc = l & 7;
      int gcc = cc ^ (row & 7);  // source-side xor swizzle
      const bf16_t* ga = Ab + (size_t)row * K + k0 + gcc * 8;
      __builtin_amdgcn_global_load_lds(TO_GLB(ga), TO_LDS(As + (it * 256 + wv * 64) * 8), 16, 0, 0);
      const bf16_t* gb = Bb + (size_t)row * K + k0 + gcc * 8;
      __builtin_amdgcn_global_load_lds(TO_GLB(gb), TO_LDS(Bs + (it * 256 + wv * 64) * 8), 16, 0, 0);
    }
    __syncthreads();
#pragma unroll
    for (int kk = 0; kk < 2; ++kk) {
      bf16x8 af[4], bfr[4];
#pragma unroll
      for (int t = 0; t < 4; ++t) {
        int ra = wm * 64 + t * 16 + m_in;
        af[t] = *(const bf16x8*)(As + ra * 64 + (((kk * 4 + q) ^ (ra & 7)) * 8));
        int rb = wn * 64 + t * 16 + m_in;
        bfr[t] = *(const bf16x8*)(Bs + rb * 64 + (((kk * 4 + q) ^ (rb & 7)) * 8));
      }
#pragma unroll
      for (int mt = 0; mt < 4; ++mt)
#pragma unroll
        for (int nt = 0; nt < 4; ++nt)
          acc[mt][nt] = __builtin_amdgcn_mfma_f32_16x16x32_bf16(af[mt], bfr[nt], acc[mt][nt], 0, 0, 0);
    }
    __syncthreads();
  }

  if (mode == 0) {
#pragma unroll
    for (int mt = 0; mt < 4; ++mt) {
      int mbase = (int)m0 + wm * 64 + mt * 16 + q * 4;  // token index, %4==0
      int b = mbase >> 12, s = mbase & 4095;
      float mk[4];
#pragma unroll
      for (int r = 0; r < 4; ++r) mk[r] = mask[b * 4096 + s + r];
#pragma unroll
      for (int nt = 0; nt < 4; ++nt) {
        int nG = (int)n0 + wn * 64 + nt * 16 + m_in;
        int proj = nG >> 10, c = nG & 1023, h = c >> 6, hd = c & 63;
        const float* bp = (proj == 0) ? bq : ((proj == 1) ? bk : bv);
        float bias = bp[c];
        if (proj == 0) {
#pragma unroll
          for (int r = 0; r < 4; ++r)
            Q[((size_t)(b * 16 + h) * 4096 + s + r) * 64 + hd] = (bf16_t)(acc[mt][nt][r] + bias);
        } else {
          bf16_t* dst = (proj == 1) ? KT : VT;
          bf16x4 v;
#pragma unroll
          for (int r = 0; r < 4; ++r) v[r] = (bf16_t)((acc[mt][nt][r] + bias) * mk[r]);
          *(bf16x4*)(dst + ((size_t)(b * 16 + h) * 64 + hd) * 4096 + s) = v;
        }
      }
    }
  } else {
#pragma unroll
    for (int mt = 0; mt < 4; ++mt) {
      int t = (int)m0 + wm * 64 + mt * 16 + q * 4;
#pragma unroll
      for (int nt = 0; nt < 4; ++nt) {
        int nG = (int)n0 + wn * 64 + nt * 16 + m_in;
        float bias = bo[nG];
#pragma unroll
        for (int r = 0; r < 4; ++r) out[(size_t)(t + r) * 1024 + nG] = acc[mt][nt][r] + bias;
      }
    }
  }
}

// ---------------- GEMM2: Kp/Vp = E_h @ (masked K/V)^T, per (b,h) ----------------
// 512 threads (8 waves), tile M=128(lk) x N=64(hd), BK=128. Grid (2, 64, 2).
// kv=0 -> Kp natural [lk][hd]; kv=1 -> Vp transposed [hd][lk].
__global__ __launch_bounds__(512) void gemm2_kernel(
    const bf16_t* __restrict__ E, const bf16_t* __restrict__ KT, const bf16_t* __restrict__ VT,
    bf16_t* __restrict__ Kp, bf16_t* __restrict__ VpT) {
  int tid = threadIdx.x, lane = tid & 63, wv = tid >> 6;  // 8 waves
  int wm = wv >> 1, wn = wv & 1;
  int q = lane >> 4, m_in = lane & 15;
  int mt0 = blockIdx.x;
  int bh = blockIdx.y;
  int kv = blockIdx.z;
  int h = bh & 15;
  const bf16_t* Ab = E + (size_t)h * 256 * 4096 + (size_t)mt0 * 128 * 4096;
  const bf16_t* Bb = (kv ? VT : KT) + (size_t)bh * 64 * 4096;
  __shared__ __align__(16) bf16_t As[4 * 128 * 32];  // 32KB, [sub][row][32]
  __shared__ __align__(16) bf16_t Bs[4 * 64 * 32];   // 16KB, [sub][row][32]

  f32x4 acc[2][2];
  f32x4 z = {0.f, 0.f, 0.f, 0.f};
#pragma unroll
  for (int mt = 0; mt < 2; ++mt)
#pragma unroll
    for (int nt = 0; nt < 2; ++nt) acc[mt][nt] = z;

  for (int k0 = 0; k0 < 4096; k0 += 128) {
#pragma unroll
    for (int it = 0; it < 4; ++it) {  // As: 2048 chunks of 16B
      int l = it * 512 + tid;
      int sub = l >> 9, row = (l >> 2) & 127, cc = l & 3;
      const bf16_t* ga = Ab + (size_t)row * 4096 + k0 + sub * 32 + cc * 8;
      __builtin_amdgcn_global_load_lds(TO_GLB(ga), TO_LDS(As + (it * 512 + wv * 64) * 8), 16, 0, 0);
    }
#pragma unroll
    for (int it = 0; it < 2; ++it) {  // Bs: 1024 chunks
      int l = it * 512 + tid;
      int sub = l >> 8, row = (l >> 2) & 63, cc = l & 3;
      const bf16_t* gb = Bb + (size_t)row * 4096 + k0 + sub * 32 + cc * 8;
      __builtin_amdgcn_global_load_lds(TO_GLB(gb), TO_LDS(Bs + (it * 512 + wv * 64) * 8), 16, 0, 0);
    }
    __syncthreads();
#pragma unroll
    for (int kk = 0; kk < 4; ++kk) {
      bf16x8 af[2], bfr[2];
#pragma unroll
      for (int mt = 0; mt < 2; ++mt)
        af[mt] = *(const bf16x8*)(As + kk * 4096 + (wm * 32 + mt * 16 + m_in) * 32 + q * 8);
#pragma unroll
      for (int nt = 0; nt < 2; ++nt)
        bfr[nt] = *(const bf16x8*)(Bs + kk * 2048 + (wn * 32 + nt * 16 + m_in) * 32 + q * 8);
#pragma unroll
      for (int mt = 0; mt < 2; ++mt)
#pragma unroll
        for (int nt = 0; nt < 2; ++nt)
          acc[mt][nt] = __builtin_amdgcn_mfma_f32_16x16x32_bf16(af[mt], bfr[nt], acc[mt][nt], 0, 0, 0);
    }
    __syncthreads();
  }

#pragma unroll
  for (int mt = 0; mt < 2; ++mt) {
    int lk = mt0 * 128 + wm * 32 + mt * 16 + q * 4;
#pragma unroll
    for (int nt = 0; nt < 2; ++nt) {
      int hd = wn * 32 + nt * 16 + m_in;
      if (kv == 0) {
#pragma unroll
        for (int r = 0; r < 4; ++r)
          Kp[(size_t)bh * 16384 + (size_t)(lk + r) * 64 + hd] = (bf16_t)acc[mt][nt][r];
      } else {
        bf16x4 v;
#pragma unroll
        for (int r = 0; r < 4; ++r) v[r] = (bf16_t)acc[mt][nt][r];
        *(bf16x4*)(VpT + (size_t)bh * 16384 + (size_t)hd * 256 + lk) = v;
      }
    }
  }
}

// ---------------- fused attention: scores -> softmax -> PV ----------------
// Grid (S/64, B*H), 256 threads (4 waves x 16 Q-rows each).
// One 32KB LDS buffer staged 3x: Kp (sub-tiled) -> P (xor-swizzled) -> Vp (sub-tiled).
__global__ __launch_bounds__(256) void attn_kernel(
    const bf16_t* __restrict__ Q, const bf16_t* __restrict__ Kp, const bf16_t* __restrict__ VpT,
    bf16_t* __restrict__ Xo) {
  int tid = threadIdx.x, lane = tid & 63, wv = tid >> 6;
  int q = lane >> 4, m_in = lane & 15;
  int s0 = blockIdx.x * 64;
  int bh = blockIdx.y;
  int b = bh >> 4, h = bh & 15;
  const bf16_t* Qb = Q + ((size_t)bh * 4096 + s0 + wv * 16) * 64;
  const bf16_t* Kpb = Kp + (size_t)bh * 16384;
  const bf16_t* Vb = VpT + (size_t)bh * 16384;
  __shared__ __align__(16) bf16_t buf[16384];  // 32KB, reused Kp -> P -> Vp

  // stage Kp [256][64] as sub-tiled [2][256][32]
#pragma unroll
  for (int it = 0; it < 8; ++it) {
    int l = it * 256 + tid;
    int sub = l >> 10, row = (l >> 2) & 255, cc = l & 3;
    const bf16_t* g = Kpb + row * 64 + sub * 32 + cc * 8;
    __builtin_amdgcn_global_load_lds(TO_GLB(g), TO_LDS(buf + (it * 256 + wv * 64) * 8), 16, 0, 0);
  }
  bf16x8 aq[2];
#pragma unroll
  for (int ks = 0; ks < 2; ++ks) aq[ks] = *(const bf16x8*)(Qb + (size_t)m_in * 64 + ks * 32 + q * 8);
  __syncthreads();  // B0: Kp staged

  f32x4 sc[16];
  f32x4 z = {0.f, 0.f, 0.f, 0.f};
#pragma unroll
  for (int nt = 0; nt < 16; ++nt) sc[nt] = z;
#pragma unroll
  for (int nt = 0; nt < 16; ++nt)
#pragma unroll
    for (int ks = 0; ks < 2; ++ks) {
      bf16x8 kb = *(const bf16x8*)(buf + ks * 8192 + (nt * 16 + m_in) * 32 + q * 8);
      sc[nt] = __builtin_amdgcn_mfma_f32_16x16x32_bf16(aq[ks], kb, sc[nt], 0, 0, 0);
    }

  // softmax over 256 (per-row: 16 frag regs x 16 lanes in quad-group)
  float mx[4], sm[4];
#pragma unroll
  for (int r = 0; r < 4; ++r) mx[r] = -1e30f;
#pragma unroll
  for (int nt = 0; nt < 16; ++nt)
#pragma unroll
    for (int r = 0; r < 4; ++r) {
      float t = sc[nt][r] * 0.125f;  // 1/sqrt(HD)
      sc[nt][r] = t;
      mx[r] = fmaxf(mx[r], t);
    }
#pragma unroll
  for (int off = 1; off < 16; off <<= 1)
#pragma unroll
    for (int r = 0; r < 4; ++r) mx[r] = fmaxf(mx[r], __shfl_xor(mx[r], off));
#pragma unroll
  for (int r = 0; r < 4; ++r) sm[r] = 0.f;
#pragma unroll
  for (int nt = 0; nt < 16; ++nt)
#pragma unroll
    for (int r = 0; r < 4; ++r) {
      float e = __expf(sc[nt][r] - mx[r]);
      sc[nt][r] = e;
      sm[r] += e;
    }
#pragma unroll
  for (int off = 1; off < 16; off <<= 1)
#pragma unroll
    for (int r = 0; r < 4; ++r) sm[r] += __shfl_xor(sm[r], off);
  float inv[4];
#pragma unroll
  for (int r = 0; r < 4; ++r) inv[r] = 1.0f / sm[r];

  __syncthreads();  // B1: all waves done reading Kp; safe to overwrite buf with P

  // write P (16x256 per wave) xor-swizzled in 16B chunks: conflict-free b128 reads
  bf16_t* Pw = buf + wv * 4096;
#pragma unroll
  for (int nt = 0; nt < 16; ++nt) {
    int cw = nt * 2 + (m_in >> 3);
#pragma unroll
    for (int r = 0; r < 4; ++r) {
      int rp = q * 4 + r;
      int sw = (((cw ^ (rp & 7)) << 3) | (m_in & 7));
      Pw[rp * 256 + sw] = (bf16_t)(sc[nt][r] * inv[r]);
    }
  }
  // read own-wave A-frags (same-wave LDS dependency, no barrier needed)
  bf16x8 pa[8];
#pragma unroll
  for (int ks = 0; ks < 8; ++ks) {
    int c = ks * 4 + q;
    pa[ks] = *(const bf16x8*)(Pw + m_in * 256 + ((c ^ (m_in & 7)) << 3));
  }
  __syncthreads();  // B2: all waves have pa in regs; safe to overwrite buf with Vp

  // stage VpT [64][256] as sub-tiled [8][64][32]
#pragma unroll
  for (int it = 0; it < 8; ++it) {
    int l = it * 256 + tid;
    int sub = l >> 8, row = (l >> 2) & 63, cc = l & 3;
    const bf16_t* g = Vb + row * 256 + sub * 32 + cc * 8;
    __builtin_amdgcn_global_load_lds(TO_GLB(g), TO_LDS(buf + (it * 256 + wv * 64) * 8), 16, 0, 0);
  }
  __syncthreads();  // B3: Vp staged

  f32x4 o[4];
#pragma unroll
  for (int nt = 0; nt < 4; ++nt) o[nt] = z;
#pragma unroll
  for (int nt = 0; nt < 4; ++nt)
#pragma unroll
    for (int ks = 0; ks < 8; ++ks) {
      bf16x8 vb = *(const bf16x8*)(buf + ks * 2048 + (nt * 16 + m_in) * 32 + q * 8);
      o[nt] = __builtin_amdgcn_mfma_f32_16x16x32_bf16(pa[ks], vb, o[nt], 0, 0, 0);
    }

#pragma unroll
  for (int nt = 0; nt < 4; ++nt)
#pragma unroll
    for (int r = 0; r < 4; ++r)
      Xo[((size_t)b * 4096 + s0 + wv * 16 + q * 4 + r) * 1024 + h * 64 + nt * 16 + m_in] =
          (bf16_t)o[nt][r];
}

extern "C" void kernel_launch(void* const* d_in, const int* in_sizes, int n_in,
                              void* d_out, int out_size, void* d_ws, size_t ws_size,
                              hipStream_t stream) {
  const float* X = (const float*)d_in[0];
  const float* mask = (const float*)d_in[1];
  const float* Wq = (const float*)d_in[2];
  const float* bq = (const float*)d_in[3];
  const float* Wk = (const float*)d_in[4];
  const float* bk = (const float*)d_in[5];
  const float* Wv = (const float*)d_in[6];
  const float* bv = (const float*)d_in[7];
  const float* E = (const float*)d_in[8];
  const float* Wo = (const float*)d_in[9];
  const float* bo = (const float*)d_in[10];
  float* out = (float*)d_out;

  char* ws = (char*)d_ws;
  const size_t SZ = 33554432;  // 16M bf16 elements
  bf16_t* Xb = (bf16_t*)(ws);              // reused as Xo after gemm1
  bf16_t* Eb = (bf16_t*)(ws + SZ);
  bf16_t* Qb = (bf16_t*)(ws + 2 * SZ);
  bf16_t* KT = (bf16_t*)(ws + 3 * SZ);     // (B,H,HD,S) masked
  bf16_t* VT = (bf16_t*)(ws + 4 * SZ);     // (B,H,HD,S) masked
  bf16_t* Kp = (bf16_t*)(ws + 5 * SZ);                 // (B,H,LK,HD)
  bf16_t* VpT = (bf16_t*)(ws + 5 * SZ + 8388608);      // (B,H,HD,LK)
  bf16_t* WqkvT = (bf16_t*)(ws + 5 * SZ + 2 * 8388608);           // (3072,1024)
  bf16_t* WoT = (bf16_t*)(ws + 5 * SZ + 2 * 8388608 + 6291456);   // (1024,1024)
  bf16_t* Xo = Xb;

  cast2_bf16_kernel<<<32768, 256, 0, stream>>>(X, Xb, E, Eb, 4194304);
  transpose_cast4<<<dim3(16, 16, 4), 256, 0, stream>>>(
      Wq, Wk, Wv, Wo, WqkvT, WqkvT + 1048576, WqkvT + 2097152, WoT);

  gemm_bt_128<<<dim3(128, 24), 256, 0, stream>>>(Xb, WqkvT, 1024, 0, bq, bk, bv, mask,
                                                 Qb, KT, VT, nullptr, nullptr);
  gemm2_kernel<<<dim3(2, 64, 2), 512, 0, stream>>>(Eb, KT, VT, Kp, VpT);
  attn_kernel<<<dim3(64, 64), 256, 0, stream>>>(Qb, Kp, VpT, Xo);
  gemm_bt_128<<<dim3(128, 8), 256, 0, stream>>>(Xo, WoT, 1024, 1, nullptr, nullptr, nullptr,
                                                nullptr, nullptr, nullptr, nullptr, bo, out);
}

// Round 4
// 460.139 us; speedup vs baseline: 1.3302x; 1.0250x over previous
//
#include <hip/hip_runtime.h>
#include <hip/hip_bf16.h>
#include <stdint.h>

// Problem constants: B=4, S=4096, D=1024, H=16, HD=64, LK=256
typedef __bf16 bf16_t;
typedef __attribute__((ext_vector_type(8))) __bf16 bf16x8;
typedef __attribute__((ext_vector_type(4))) __bf16 bf16x4;
typedef __attribute__((ext_vector_type(4))) float f32x4;

#define TO_GLB(p) ((const __attribute__((address_space(1))) void*)(p))
#define TO_LDS(p) ((__attribute__((address_space(3))) void*)(p))

// ---------------- cast fp32 -> bf16, two tensors in one launch ----------------
__global__ __launch_bounds__(256) void cast2_bf16_kernel(const float* __restrict__ a,
                                                         bf16_t* __restrict__ da,
                                                         const float* __restrict__ b,
                                                         bf16_t* __restrict__ db, int n4) {
  int i = blockIdx.x * 256 + threadIdx.x;
  const float* s = (i < n4) ? a : b;
  bf16_t* d = (i < n4) ? da : db;
  int j = (i < n4) ? i : i - n4;
  float4 v = ((const float4*)s)[j];
  bf16x4 o;
  o[0] = (bf16_t)v.x; o[1] = (bf16_t)v.y; o[2] = (bf16_t)v.z; o[3] = (bf16_t)v.w;
  ((bf16x4*)d)[j] = o;
}

// ---------------- transpose-cast 4 square matrices (1024x1024) in one launch ----------------
__global__ __launch_bounds__(256) void transpose_cast4(
    const float* __restrict__ W0, const float* __restrict__ W1, const float* __restrict__ W2,
    const float* __restrict__ W3, bf16_t* __restrict__ o0, bf16_t* __restrict__ o1,
    bf16_t* __restrict__ o2, bf16_t* __restrict__ o3) {
  const int RC = 1024;
  __shared__ bf16_t tile[64][72];
  int z = blockIdx.z;
  const float* W = (z == 0) ? W0 : (z == 1) ? W1 : (z == 2) ? W2 : W3;
  bf16_t* out = (z == 0) ? o0 : (z == 1) ? o1 : (z == 2) ? o2 : o3;
  int r0 = blockIdx.y * 64, c0 = blockIdx.x * 64;
  int tid = threadIdx.x;
#pragma unroll
  for (int p = 0; p < 4; ++p) {
    int r = p * 16 + (tid >> 4);
    int c = (tid & 15) * 4;
    float4 v = *(const float4*)(W + (size_t)(r0 + r) * RC + c0 + c);
    tile[r][c + 0] = (bf16_t)v.x; tile[r][c + 1] = (bf16_t)v.y;
    tile[r][c + 2] = (bf16_t)v.z; tile[r][c + 3] = (bf16_t)v.w;
  }
  __syncthreads();
#pragma unroll
  for (int p = 0; p < 4; ++p) {
    int c = p * 16 + (tid >> 4);
    int r = (tid & 15) * 4;
    bf16x4 o;
    o[0] = tile[r + 0][c]; o[1] = tile[r + 1][c];
    o[2] = tile[r + 2][c]; o[3] = tile[r + 3][c];
    *(bf16x4*)(out + (size_t)(c0 + c) * RC + r0 + r) = o;
  }
}

// ---------------- 256x128xBK64 bf16 GEMM, C = A @ B^T (both [row][k]) ----------------
// 512 threads, 8 waves (4m x 2n), each wave 64x64 out. LDS xor-swizzled at global
// source (cc^(row&7)) so DMA dest stays lane-contiguous and frag reads conflict-free.
// mode 0: QKV projection epilogue; mode 1: output projection epilogue (+bo, fp32)
__global__ __launch_bounds__(512) void gemm_bt_256(
    const bf16_t* __restrict__ A, const bf16_t* __restrict__ B, int K, int mode,
    const float* __restrict__ bq, const float* __restrict__ bk, const float* __restrict__ bv,
    const float* __restrict__ mask,
    bf16_t* __restrict__ Q, bf16_t* __restrict__ KT, bf16_t* __restrict__ VT,
    const float* __restrict__ bo, float* __restrict__ out) {
  int tid = threadIdx.x;
  int lane = tid & 63, wv = tid >> 6;  // 8 waves
  int wm = wv >> 1, wn = wv & 1;
  int q = lane >> 4, m_in = lane & 15;
  size_t m0 = (size_t)blockIdx.x * 256;
  size_t n0 = (size_t)blockIdx.y * 128;
  const bf16_t* Ab = A + m0 * K;
  const bf16_t* Bb = B + n0 * K;
  __shared__ __align__(16) bf16_t As[256 * 64];  // 32KB
  __shared__ __align__(16) bf16_t Bs[128 * 64];  // 16KB

  f32x4 acc[4][4];
  f32x4 z = {0.f, 0.f, 0.f, 0.f};
#pragma unroll
  for (int mt = 0; mt < 4; ++mt)
#pragma unroll
    for (int nt = 0; nt < 4; ++nt) acc[mt][nt] = z;

  for (int k0 = 0; k0 < K; k0 += 64) {
#pragma unroll
    for (int it = 0; it < 4; ++it) {  // As: 2048 chunks of 16B
      int l = it * 512 + tid;
      int row = l >> 3, cc = (l & 7) ^ (row & 7);
      const bf16_t* ga = Ab + (size_t)row * K + k0 + cc * 8;
      __builtin_amdgcn_global_load_lds(TO_GLB(ga), TO_LDS(As + (it * 512 + wv * 64) * 8), 16, 0, 0);
    }
#pragma unroll
    for (int it = 0; it < 2; ++it) {  // Bs: 1024 chunks
      int l = it * 512 + tid;
      int row = l >> 3, cc = (l & 7) ^ (row & 7);
      const bf16_t* gb = Bb + (size_t)row * K + k0 + cc * 8;
      __builtin_amdgcn_global_load_lds(TO_GLB(gb), TO_LDS(Bs + (it * 512 + wv * 64) * 8), 16, 0, 0);
    }
    __syncthreads();
#pragma unroll
    for (int kk = 0; kk < 2; ++kk) {
      bf16x8 af[4], bfr[4];
#pragma unroll
      for (int t = 0; t < 4; ++t) {
        int ra = wm * 64 + t * 16 + m_in;
        af[t] = *(const bf16x8*)(As + ra * 64 + (((kk * 4 + q) ^ (ra & 7)) * 8));
        int rb = wn * 64 + t * 16 + m_in;
        bfr[t] = *(const bf16x8*)(Bs + rb * 64 + (((kk * 4 + q) ^ (rb & 7)) * 8));
      }
#pragma unroll
      for (int mt = 0; mt < 4; ++mt)
#pragma unroll
        for (int nt = 0; nt < 4; ++nt)
          acc[mt][nt] = __builtin_amdgcn_mfma_f32_16x16x32_bf16(af[mt], bfr[nt], acc[mt][nt], 0, 0, 0);
    }
    __syncthreads();
  }

  if (mode == 0) {
#pragma unroll
    for (int mt = 0; mt < 4; ++mt) {
      int mbase = (int)m0 + wm * 64 + mt * 16 + q * 4;  // token index, %4==0
      int b = mbase >> 12, s = mbase & 4095;
      float mk[4];
#pragma unroll
      for (int r = 0; r < 4; ++r) mk[r] = mask[b * 4096 + s + r];
#pragma unroll
      for (int nt = 0; nt < 4; ++nt) {
        int nG = (int)n0 + wn * 64 + nt * 16 + m_in;
        int proj = nG >> 10, c = nG & 1023, h = c >> 6, hd = c & 63;
        const float* bp = (proj == 0) ? bq : ((proj == 1) ? bk : bv);
        float bias = bp[c];
        if (proj == 0) {
#pragma unroll
          for (int r = 0; r < 4; ++r)
            Q[((size_t)(b * 16 + h) * 4096 + s + r) * 64 + hd] = (bf16_t)(acc[mt][nt][r] + bias);
        } else {
          bf16_t* dst = (proj == 1) ? KT : VT;
          bf16x4 v;
#pragma unroll
          for (int r = 0; r < 4; ++r) v[r] = (bf16_t)((acc[mt][nt][r] + bias) * mk[r]);
          *(bf16x4*)(dst + ((size_t)(b * 16 + h) * 64 + hd) * 4096 + s) = v;
        }
      }
    }
  } else {
#pragma unroll
    for (int mt = 0; mt < 4; ++mt) {
      int t = (int)m0 + wm * 64 + mt * 16 + q * 4;
#pragma unroll
      for (int nt = 0; nt < 4; ++nt) {
        int nG = (int)n0 + wn * 64 + nt * 16 + m_in;
        float bias = bo[nG];
#pragma unroll
        for (int r = 0; r < 4; ++r) out[(size_t)(t + r) * 1024 + nG] = acc[mt][nt][r] + bias;
      }
    }
  }
}

// ---------------- GEMM2 split-K: partial = E_h @ (masked K/V chunk)^T ----------------
// Grid (2 mt, 64 bh, 8 = kv*4+kc), 512 threads. Each block contracts S-chunk of 1024,
// writes fp32 partial [lk][hd] to Pp at ((bh*2+kv)*4+kc). Deterministic (no atomics).
__global__ __launch_bounds__(512) void gemm2_kernel(
    const bf16_t* __restrict__ E, const bf16_t* __restrict__ KT, const bf16_t* __restrict__ VT,
    float* __restrict__ Pp) {
  int tid = threadIdx.x, lane = tid & 63, wv = tid >> 6;  // 8 waves
  int wm = wv >> 1, wn = wv & 1;
  int q = lane >> 4, m_in = lane & 15;
  int mt0 = blockIdx.x;
  int bh = blockIdx.y;
  int kv = blockIdx.z >> 2, kc = blockIdx.z & 3;
  int h = bh & 15;
  const bf16_t* Ab = E + (size_t)h * 256 * 4096 + (size_t)mt0 * 128 * 4096 + kc * 1024;
  const bf16_t* Bb = (kv ? VT : KT) + (size_t)bh * 64 * 4096 + kc * 1024;
  __shared__ __align__(16) bf16_t As[4 * 128 * 32];  // 32KB, [sub][row][32]
  __shared__ __align__(16) bf16_t Bs[4 * 64 * 32];   // 16KB, [sub][row][32]

  f32x4 acc[2][2];
  f32x4 z = {0.f, 0.f, 0.f, 0.f};
#pragma unroll
  for (int mt = 0; mt < 2; ++mt)
#pragma unroll
    for (int nt = 0; nt < 2; ++nt) acc[mt][nt] = z;

  for (int k0 = 0; k0 < 1024; k0 += 128) {
#pragma unroll
    for (int it = 0; it < 4; ++it) {  // As: 2048 chunks of 16B
      int l = it * 512 + tid;
      int sub = l >> 9, row = (l >> 2) & 127, cc = l & 3;
      const bf16_t* ga = Ab + (size_t)row * 4096 + k0 + sub * 32 + cc * 8;
      __builtin_amdgcn_global_load_lds(TO_GLB(ga), TO_LDS(As + (it * 512 + wv * 64) * 8), 16, 0, 0);
    }
#pragma unroll
    for (int it = 0; it < 2; ++it) {  // Bs: 1024 chunks
      int l = it * 512 + tid;
      int sub = l >> 8, row = (l >> 2) & 63, cc = l & 3;
      const bf16_t* gb = Bb + (size_t)row * 4096 + k0 + sub * 32 + cc * 8;
      __builtin_amdgcn_global_load_lds(TO_GLB(gb), TO_LDS(Bs + (it * 512 + wv * 64) * 8), 16, 0, 0);
    }
    __syncthreads();
#pragma unroll
    for (int kk = 0; kk < 4; ++kk) {
      bf16x8 af[2], bfr[2];
#pragma unroll
      for (int mt = 0; mt < 2; ++mt)
        af[mt] = *(const bf16x8*)(As + kk * 4096 + (wm * 32 + mt * 16 + m_in) * 32 + q * 8);
#pragma unroll
      for (int nt = 0; nt < 2; ++nt)
        bfr[nt] = *(const bf16x8*)(Bs + kk * 2048 + (wn * 32 + nt * 16 + m_in) * 32 + q * 8);
#pragma unroll
      for (int mt = 0; mt < 2; ++mt)
#pragma unroll
        for (int nt = 0; nt < 2; ++nt)
          acc[mt][nt] = __builtin_amdgcn_mfma_f32_16x16x32_bf16(af[mt], bfr[nt], acc[mt][nt], 0, 0, 0);
    }
    __syncthreads();
  }

  float* P = Pp + ((size_t)(bh * 2 + kv) * 4 + kc) * 16384;
#pragma unroll
  for (int mt = 0; mt < 2; ++mt) {
    int lk = mt0 * 128 + wm * 32 + mt * 16 + q * 4;
#pragma unroll
    for (int nt = 0; nt < 2; ++nt) {
      int hd = wn * 32 + nt * 16 + m_in;
#pragma unroll
      for (int r = 0; r < 4; ++r) P[(size_t)(lk + r) * 64 + hd] = acc[mt][nt][r];
    }
  }
}

// ---------------- reduce 4 split-K partials -> Kp bf16 [lk][hd], VpT bf16 [hd][lk] ----------------
// Grid (64 bh, 2 kv), 256 threads.
__global__ __launch_bounds__(256) void gemm2_reduce(const float* __restrict__ Pp,
                                                    bf16_t* __restrict__ Kp,
                                                    bf16_t* __restrict__ VpT) {
  int bh = blockIdx.x, kv = blockIdx.y;
  int tid = threadIdx.x;
  const float* P = Pp + ((size_t)(bh * 2 + kv) * 4) * 16384;
#pragma unroll
  for (int it = 0; it < 16; ++it) {
    int e4 = it * 256 + tid;  // f32x4 index within 16384
    f32x4 s = *(const f32x4*)(P + e4 * 4);
    f32x4 s1 = *(const f32x4*)(P + 16384 + e4 * 4);
    f32x4 s2 = *(const f32x4*)(P + 32768 + e4 * 4);
    f32x4 s3 = *(const f32x4*)(P + 49152 + e4 * 4);
    s += s1; s += s2; s += s3;
    if (kv == 0) {
      bf16x4 v;
#pragma unroll
      for (int r = 0; r < 4; ++r) v[r] = (bf16_t)s[r];
      *(bf16x4*)(Kp + (size_t)bh * 16384 + e4 * 4) = v;
    } else {
      int lk = (e4 * 4) >> 6, hd = (e4 * 4) & 63;
      bf16_t* d = VpT + (size_t)bh * 16384 + lk;
#pragma unroll
      for (int r = 0; r < 4; ++r) d[(size_t)(hd + r) * 256] = (bf16_t)s[r];
    }
  }
}

// ---------------- fused attention: scores -> softmax -> PV ----------------
// Grid (S/64, B*H), 256 threads (4 waves x 16 Q-rows each).
__global__ __launch_bounds__(256) void attn_kernel(
    const bf16_t* __restrict__ Q, const bf16_t* __restrict__ Kp, const bf16_t* __restrict__ VpT,
    bf16_t* __restrict__ Xo) {
  int tid = threadIdx.x, lane = tid & 63, wv = tid >> 6;
  int q = lane >> 4, m_in = lane & 15;
  int s0 = blockIdx.x * 64;
  int bh = blockIdx.y;
  int b = bh >> 4, h = bh & 15;
  const bf16_t* Qb = Q + ((size_t)bh * 4096 + s0 + wv * 16) * 64;
  const bf16_t* Kpb = Kp + (size_t)bh * 16384;
  const bf16_t* Vb = VpT + (size_t)bh * 16384;
  __shared__ __align__(16) bf16_t buf[16384];  // 32KB, reused Kp -> P -> Vp

#pragma unroll
  for (int it = 0; it < 8; ++it) {
    int l = it * 256 + tid;
    int sub = l >> 10, row = (l >> 2) & 255, cc = l & 3;
    const bf16_t* g = Kpb + row * 64 + sub * 32 + cc * 8;
    __builtin_amdgcn_global_load_lds(TO_GLB(g), TO_LDS(buf + (it * 256 + wv * 64) * 8), 16, 0, 0);
  }
  bf16x8 aq[2];
#pragma unroll
  for (int ks = 0; ks < 2; ++ks) aq[ks] = *(const bf16x8*)(Qb + (size_t)m_in * 64 + ks * 32 + q * 8);
  __syncthreads();  // B0: Kp staged

  f32x4 sc[16];
  f32x4 z = {0.f, 0.f, 0.f, 0.f};
#pragma unroll
  for (int nt = 0; nt < 16; ++nt) sc[nt] = z;
#pragma unroll
  for (int nt = 0; nt < 16; ++nt)
#pragma unroll
    for (int ks = 0; ks < 2; ++ks) {
      bf16x8 kb = *(const bf16x8*)(buf + ks * 8192 + (nt * 16 + m_in) * 32 + q * 8);
      sc[nt] = __builtin_amdgcn_mfma_f32_16x16x32_bf16(aq[ks], kb, sc[nt], 0, 0, 0);
    }

  float mx[4], sm[4];
#pragma unroll
  for (int r = 0; r < 4; ++r) mx[r] = -1e30f;
#pragma unroll
  for (int nt = 0; nt < 16; ++nt)
#pragma unroll
    for (int r = 0; r < 4; ++r) {
      float t = sc[nt][r] * 0.125f;  // 1/sqrt(HD)
      sc[nt][r] = t;
      mx[r] = fmaxf(mx[r], t);
    }
#pragma unroll
  for (int off = 1; off < 16; off <<= 1)
#pragma unroll
    for (int r = 0; r < 4; ++r) mx[r] = fmaxf(mx[r], __shfl_xor(mx[r], off));
#pragma unroll
  for (int r = 0; r < 4; ++r) sm[r] = 0.f;
#pragma unroll
  for (int nt = 0; nt < 16; ++nt)
#pragma unroll
    for (int r = 0; r < 4; ++r) {
      float e = __expf(sc[nt][r] - mx[r]);
      sc[nt][r] = e;
      sm[r] += e;
    }
#pragma unroll
  for (int off = 1; off < 16; off <<= 1)
#pragma unroll
    for (int r = 0; r < 4; ++r) sm[r] += __shfl_xor(sm[r], off);
  float inv[4];
#pragma unroll
  for (int r = 0; r < 4; ++r) inv[r] = 1.0f / sm[r];

  __syncthreads();  // B1: all waves done reading Kp

  bf16_t* Pw = buf + wv * 4096;
#pragma unroll
  for (int nt = 0; nt < 16; ++nt) {
    int cw = nt * 2 + (m_in >> 3);
#pragma unroll
    for (int r = 0; r < 4; ++r) {
      int rp = q * 4 + r;
      int sw = (((cw ^ (rp & 7)) << 3) | (m_in & 7));
      Pw[rp * 256 + sw] = (bf16_t)(sc[nt][r] * inv[r]);
    }
  }
  bf16x8 pa[8];
#pragma unroll
  for (int ks = 0; ks < 8; ++ks) {
    int c = ks * 4 + q;
    pa[ks] = *(const bf16x8*)(Pw + m_in * 256 + ((c ^ (m_in & 7)) << 3));
  }
  __syncthreads();  // B2: all waves hold pa

#pragma unroll
  for (int it = 0; it < 8; ++it) {
    int l = it * 256 + tid;
    int sub = l >> 8, row = (l >> 2) & 63, cc = l & 3;
    const bf16_t* g = Vb + row * 256 + sub * 32 + cc * 8;
    __builtin_amdgcn_global_load_lds(TO_GLB(g), TO_LDS(buf + (it * 256 + wv * 64) * 8), 16, 0, 0);
  }
  __syncthreads();  // B3: Vp staged

  f32x4 o[4];
#pragma unroll
  for (int nt = 0; nt < 4; ++nt) o[nt] = z;
#pragma unroll
  for (int nt = 0; nt < 4; ++nt)
#pragma unroll
    for (int ks = 0; ks < 8; ++ks) {
      bf16x8 vb = *(const bf16x8*)(buf + ks * 2048 + (nt * 16 + m_in) * 32 + q * 8);
      o[nt] = __builtin_amdgcn_mfma_f32_16x16x32_bf16(pa[ks], vb, o[nt], 0, 0, 0);
    }

#pragma unroll
  for (int nt = 0; nt < 4; ++nt)
#pragma unroll
    for (int r = 0; r < 4; ++r)
      Xo[((size_t)b * 4096 + s0 + wv * 16 + q * 4 + r) * 1024 + h * 64 + nt * 16 + m_in] =
          (bf16_t)o[nt][r];
}

extern "C" void kernel_launch(void* const* d_in, const int* in_sizes, int n_in,
                              void* d_out, int out_size, void* d_ws, size_t ws_size,
                              hipStream_t stream) {
  const float* X = (const float*)d_in[0];
  const float* mask = (const float*)d_in[1];
  const float* Wq = (const float*)d_in[2];
  const float* bq = (const float*)d_in[3];
  const float* Wk = (const float*)d_in[4];
  const float* bk = (const float*)d_in[5];
  const float* Wv = (const float*)d_in[6];
  const float* bv = (const float*)d_in[7];
  const float* E = (const float*)d_in[8];
  const float* Wo = (const float*)d_in[9];
  const float* bo = (const float*)d_in[10];
  float* out = (float*)d_out;

  char* ws = (char*)d_ws;
  const size_t SZ = 33554432;  // 32 MB
  bf16_t* Xb = (bf16_t*)(ws);                 // Xb -> gemm2 partials (fp32) -> Xo
  float* Pp = (float*)(ws);                   // 32 MB of fp32 partials (alias, Xb dead)
  bf16_t* Eb = (bf16_t*)(ws + SZ);
  bf16_t* Qb = (bf16_t*)(ws + 2 * SZ);
  bf16_t* KT = (bf16_t*)(ws + 3 * SZ);        // (B,H,HD,S) masked
  bf16_t* VT = (bf16_t*)(ws + 4 * SZ);        // (B,H,HD,S) masked
  bf16_t* Kp = (bf16_t*)(ws + 5 * SZ);                 // (B,H,LK,HD)
  bf16_t* VpT = (bf16_t*)(ws + 5 * SZ + 8388608);      // (B,H,HD,LK)
  bf16_t* WqkvT = (bf16_t*)(ws + 5 * SZ + 2 * 8388608);           // (3072,1024)
  bf16_t* WoT = (bf16_t*)(ws + 5 * SZ + 2 * 8388608 + 6291456);   // (1024,1024)
  bf16_t* Xo = Xb;

  cast2_bf16_kernel<<<32768, 256, 0, stream>>>(X, Xb, E, Eb, 4194304);
  transpose_cast4<<<dim3(16, 16, 4), 256, 0, stream>>>(
      Wq, Wk, Wv, Wo, WqkvT, WqkvT + 1048576, WqkvT + 2097152, WoT);

  gemm_bt_256<<<dim3(64, 24), 512, 0, stream>>>(Xb, WqkvT, 1024, 0, bq, bk, bv, mask,
                                                Qb, KT, VT, nullptr, nullptr);
  gemm2_kernel<<<dim3(2, 64, 8), 512, 0, stream>>>(Eb, KT, VT, Pp);
  gemm2_reduce<<<dim3(64, 2), 256, 0, stream>>>(Pp, Kp, VpT);
  attn_kernel<<<dim3(64, 64), 256, 0, stream>>>(Qb, Kp, VpT, Xo);
  gemm_bt_256<<<dim3(64, 8), 512, 0, stream>>>(Xo, WoT, 1024, 1, nullptr, nullptr, nullptr,
                                               nullptr, nullptr, nullptr, nullptr, bo, out);
}

// Round 5
// 457.027 us; speedup vs baseline: 1.3393x; 1.0068x over previous
//
#include <hip/hip_runtime.h>
#include <hip/hip_bf16.h>
#include <stdint.h>

// Problem constants: B=4, S=4096, D=1024, H=16, HD=64, LK=256
typedef __bf16 bf16_t;
typedef __attribute__((ext_vector_type(8))) __bf16 bf16x8;
typedef __attribute__((ext_vector_type(4))) __bf16 bf16x4;
typedef __attribute__((ext_vector_type(4))) float f32x4;

#define TO_GLB(p) ((const __attribute__((address_space(1))) void*)(p))
#define TO_LDS(p) ((__attribute__((address_space(3))) void*)(p))

// ---------------- cast fp32 -> bf16, two tensors in one launch ----------------
__global__ __launch_bounds__(256) void cast2_bf16_kernel(const float* __restrict__ a,
                                                         bf16_t* __restrict__ da,
                                                         const float* __restrict__ b,
                                                         bf16_t* __restrict__ db, int n4) {
  int i = blockIdx.x * 256 + threadIdx.x;
  const float* s = (i < n4) ? a : b;
  bf16_t* d = (i < n4) ? da : db;
  int j = (i < n4) ? i : i - n4;
  float4 v = ((const float4*)s)[j];
  bf16x4 o;
  o[0] = (bf16_t)v.x; o[1] = (bf16_t)v.y; o[2] = (bf16_t)v.z; o[3] = (bf16_t)v.w;
  ((bf16x4*)d)[j] = o;
}

// ---------------- transpose-cast 4 square matrices (1024x1024) in one launch ----------------
__global__ __launch_bounds__(256) void transpose_cast4(
    const float* __restrict__ W0, const float* __restrict__ W1, const float* __restrict__ W2,
    const float* __restrict__ W3, bf16_t* __restrict__ o0, bf16_t* __restrict__ o1,
    bf16_t* __restrict__ o2, bf16_t* __restrict__ o3) {
  const int RC = 1024;
  __shared__ bf16_t tile[64][72];
  int z = blockIdx.z;
  const float* W = (z == 0) ? W0 : (z == 1) ? W1 : (z == 2) ? W2 : W3;
  bf16_t* out = (z == 0) ? o0 : (z == 1) ? o1 : (z == 2) ? o2 : o3;
  int r0 = blockIdx.y * 64, c0 = blockIdx.x * 64;
  int tid = threadIdx.x;
#pragma unroll
  for (int p = 0; p < 4; ++p) {
    int r = p * 16 + (tid >> 4);
    int c = (tid & 15) * 4;
    float4 v = *(const float4*)(W + (size_t)(r0 + r) * RC + c0 + c);
    tile[r][c + 0] = (bf16_t)v.x; tile[r][c + 1] = (bf16_t)v.y;
    tile[r][c + 2] = (bf16_t)v.z; tile[r][c + 3] = (bf16_t)v.w;
  }
  __syncthreads();
#pragma unroll
  for (int p = 0; p < 4; ++p) {
    int c = p * 16 + (tid >> 4);
    int r = (tid & 15) * 4;
    bf16x4 o;
    o[0] = tile[r + 0][c]; o[1] = tile[r + 1][c];
    o[2] = tile[r + 2][c]; o[3] = tile[r + 3][c];
    *(bf16x4*)(out + (size_t)(c0 + c) * RC + r0 + r) = o;
  }
}

// ---------------- 256x128xBK64 bf16 GEMM, C = A @ B^T (both [row][k]) ----------------
// 512 threads, 8 waves (4m x 2n). LDS 128B rows, xor-swizzled at global source.
// mode 0: QKV projection epilogue; mode 1: output projection epilogue (+bo, fp32)
__global__ __launch_bounds__(512) void gemm_bt_256(
    const bf16_t* __restrict__ A, const bf16_t* __restrict__ B, int K, int mode,
    const float* __restrict__ bq, const float* __restrict__ bk, const float* __restrict__ bv,
    const float* __restrict__ mask,
    bf16_t* __restrict__ Q, bf16_t* __restrict__ KT, bf16_t* __restrict__ VT,
    const float* __restrict__ bo, float* __restrict__ out) {
  int tid = threadIdx.x;
  int lane = tid & 63, wv = tid >> 6;  // 8 waves
  int wm = wv >> 1, wn = wv & 1;
  int q = lane >> 4, m_in = lane & 15;
  size_t m0 = (size_t)blockIdx.x * 256;
  size_t n0 = (size_t)blockIdx.y * 128;
  const bf16_t* Ab = A + m0 * K;
  const bf16_t* Bb = B + n0 * K;
  __shared__ __align__(16) bf16_t As[256 * 64];  // 32KB
  __shared__ __align__(16) bf16_t Bs[128 * 64];  // 16KB

  f32x4 acc[4][4];
  f32x4 z = {0.f, 0.f, 0.f, 0.f};
#pragma unroll
  for (int mt = 0; mt < 4; ++mt)
#pragma unroll
    for (int nt = 0; nt < 4; ++nt) acc[mt][nt] = z;

  for (int k0 = 0; k0 < K; k0 += 64) {
#pragma unroll
    for (int it = 0; it < 4; ++it) {  // As: 2048 chunks of 16B
      int l = it * 512 + tid;
      int row = l >> 3, cc = (l & 7) ^ (row & 7);
      const bf16_t* ga = Ab + (size_t)row * K + k0 + cc * 8;
      __builtin_amdgcn_global_load_lds(TO_GLB(ga), TO_LDS(As + (it * 512 + wv * 64) * 8), 16, 0, 0);
    }
#pragma unroll
    for (int it = 0; it < 2; ++it) {  // Bs: 1024 chunks
      int l = it * 512 + tid;
      int row = l >> 3, cc = (l & 7) ^ (row & 7);
      const bf16_t* gb = Bb + (size_t)row * K + k0 + cc * 8;
      __builtin_amdgcn_global_load_lds(TO_GLB(gb), TO_LDS(Bs + (it * 512 + wv * 64) * 8), 16, 0, 0);
    }
    __syncthreads();
#pragma unroll
    for (int kk = 0; kk < 2; ++kk) {
      bf16x8 af[4], bfr[4];
#pragma unroll
      for (int t = 0; t < 4; ++t) {
        int ra = wm * 64 + t * 16 + m_in;
        af[t] = *(const bf16x8*)(As + ra * 64 + (((kk * 4 + q) ^ (ra & 7)) * 8));
        int rb = wn * 64 + t * 16 + m_in;
        bfr[t] = *(const bf16x8*)(Bs + rb * 64 + (((kk * 4 + q) ^ (rb & 7)) * 8));
      }
#pragma unroll
      for (int mt = 0; mt < 4; ++mt)
#pragma unroll
        for (int nt = 0; nt < 4; ++nt)
          acc[mt][nt] = __builtin_amdgcn_mfma_f32_16x16x32_bf16(af[mt], bfr[nt], acc[mt][nt], 0, 0, 0);
    }
    __syncthreads();
  }

  if (mode == 0) {
#pragma unroll
    for (int mt = 0; mt < 4; ++mt) {
      int mbase = (int)m0 + wm * 64 + mt * 16 + q * 4;  // token index, %4==0
      int b = mbase >> 12, s = mbase & 4095;
      float mk[4];
#pragma unroll
      for (int r = 0; r < 4; ++r) mk[r] = mask[b * 4096 + s + r];
#pragma unroll
      for (int nt = 0; nt < 4; ++nt) {
        int nG = (int)n0 + wn * 64 + nt * 16 + m_in;
        int proj = nG >> 10, c = nG & 1023, h = c >> 6, hd = c & 63;
        const float* bp = (proj == 0) ? bq : ((proj == 1) ? bk : bv);
        float bias = bp[c];
        if (proj == 0) {
#pragma unroll
          for (int r = 0; r < 4; ++r)
            Q[((size_t)(b * 16 + h) * 4096 + s + r) * 64 + hd] = (bf16_t)(acc[mt][nt][r] + bias);
        } else {
          bf16_t* dst = (proj == 1) ? KT : VT;
          bf16x4 v;
#pragma unroll
          for (int r = 0; r < 4; ++r) v[r] = (bf16_t)((acc[mt][nt][r] + bias) * mk[r]);
          *(bf16x4*)(dst + ((size_t)(b * 16 + h) * 64 + hd) * 4096 + s) = v;
        }
      }
    }
  } else {
#pragma unroll
    for (int mt = 0; mt < 4; ++mt) {
      int t = (int)m0 + wm * 64 + mt * 16 + q * 4;
#pragma unroll
      for (int nt = 0; nt < 4; ++nt) {
        int nG = (int)n0 + wn * 64 + nt * 16 + m_in;
        float bias = bo[nG];
#pragma unroll
        for (int r = 0; r < 4; ++r) out[(size_t)(t + r) * 1024 + nG] = acc[mt][nt][r] + bias;
      }
    }
  }
}

// ---------------- GEMM2 split-K: partial = E_h @ (masked K/V chunk)^T ----------------
// Grid (2 mt, 64 bh, 8 = kv*4+kc), 512 threads, BK=128.
// LDS [kkblk(2)][row][64]: 128B rows, xor-swizzled (same scheme as gemm_bt_256).
__global__ __launch_bounds__(512) void gemm2_kernel(
    const bf16_t* __restrict__ E, const bf16_t* __restrict__ KT, const bf16_t* __restrict__ VT,
    float* __restrict__ Pp) {
  int tid = threadIdx.x, lane = tid & 63, wv = tid >> 6;  // 8 waves
  int wm = wv >> 1, wn = wv & 1;
  int q = lane >> 4, m_in = lane & 15;
  int mt0 = blockIdx.x;
  int bh = blockIdx.y;
  int kv = blockIdx.z >> 2, kc = blockIdx.z & 3;
  int h = bh & 15;
  const bf16_t* Ab = E + (size_t)h * 256 * 4096 + (size_t)mt0 * 128 * 4096 + kc * 1024;
  const bf16_t* Bb = (kv ? VT : KT) + (size_t)bh * 64 * 4096 + kc * 1024;
  __shared__ __align__(16) bf16_t As[2 * 128 * 64];  // 32KB, [kkblk][row][64]
  __shared__ __align__(16) bf16_t Bs[2 * 64 * 64];   // 16KB, [kkblk][row][64]

  f32x4 acc[2][2];
  f32x4 z = {0.f, 0.f, 0.f, 0.f};
#pragma unroll
  for (int mt = 0; mt < 2; ++mt)
#pragma unroll
    for (int nt = 0; nt < 2; ++nt) acc[mt][nt] = z;

  for (int k0 = 0; k0 < 1024; k0 += 128) {
#pragma unroll
    for (int it = 0; it < 4; ++it) {  // As: 2048 chunks of 16B
      int l = it * 512 + tid;
      int kkb = l >> 10, row = (l >> 3) & 127, cc = (l & 7) ^ (row & 7);
      const bf16_t* ga = Ab + (size_t)row * 4096 + k0 + kkb * 64 + cc * 8;
      __builtin_amdgcn_global_load_lds(TO_GLB(ga), TO_LDS(As + (it * 512 + wv * 64) * 8), 16, 0, 0);
    }
#pragma unroll
    for (int it = 0; it < 2; ++it) {  // Bs: 1024 chunks
      int l = it * 512 + tid;
      int kkb = l >> 9, row = (l >> 3) & 63, cc = (l & 7) ^ (row & 7);
      const bf16_t* gb = Bb + (size_t)row * 4096 + k0 + kkb * 64 + cc * 8;
      __builtin_amdgcn_global_load_lds(TO_GLB(gb), TO_LDS(Bs + (it * 512 + wv * 64) * 8), 16, 0, 0);
    }
    __syncthreads();
#pragma unroll
    for (int kk4 = 0; kk4 < 4; ++kk4) {
      int kkb = kk4 >> 1, qq = (kk4 & 1) * 4 + q;
      bf16x8 af[2], bfr[2];
#pragma unroll
      for (int mt = 0; mt < 2; ++mt) {
        int ra = wm * 32 + mt * 16 + m_in;
        af[mt] = *(const bf16x8*)(As + kkb * 8192 + ra * 64 + ((qq ^ (ra & 7)) * 8));
      }
#pragma unroll
      for (int nt = 0; nt < 2; ++nt) {
        int rb = wn * 32 + nt * 16 + m_in;
        bfr[nt] = *(const bf16x8*)(Bs + kkb * 4096 + rb * 64 + ((qq ^ (rb & 7)) * 8));
      }
#pragma unroll
      for (int mt = 0; mt < 2; ++mt)
#pragma unroll
        for (int nt = 0; nt < 2; ++nt)
          acc[mt][nt] = __builtin_amdgcn_mfma_f32_16x16x32_bf16(af[mt], bfr[nt], acc[mt][nt], 0, 0, 0);
    }
    __syncthreads();
  }

  float* P = Pp + ((size_t)(bh * 2 + kv) * 4 + kc) * 16384;
#pragma unroll
  for (int mt = 0; mt < 2; ++mt) {
    int lk = mt0 * 128 + wm * 32 + mt * 16 + q * 4;
#pragma unroll
    for (int nt = 0; nt < 2; ++nt) {
      int hd = wn * 32 + nt * 16 + m_in;
#pragma unroll
      for (int r = 0; r < 4; ++r) P[(size_t)(lk + r) * 64 + hd] = acc[mt][nt][r];
    }
  }
}

// ---------------- reduce 4 split-K partials -> Kp bf16 [lk][hd], VpT bf16 [hd][lk] ----------------
__global__ __launch_bounds__(256) void gemm2_reduce(const float* __restrict__ Pp,
                                                    bf16_t* __restrict__ Kp,
                                                    bf16_t* __restrict__ VpT) {
  int bh = blockIdx.x, kv = blockIdx.y;
  int tid = threadIdx.x;
  const float* P = Pp + ((size_t)(bh * 2 + kv) * 4) * 16384;
#pragma unroll
  for (int it = 0; it < 16; ++it) {
    int e4 = it * 256 + tid;  // f32x4 index within 16384
    f32x4 s = *(const f32x4*)(P + e4 * 4);
    f32x4 s1 = *(const f32x4*)(P + 16384 + e4 * 4);
    f32x4 s2 = *(const f32x4*)(P + 32768 + e4 * 4);
    f32x4 s3 = *(const f32x4*)(P + 49152 + e4 * 4);
    s += s1; s += s2; s += s3;
    if (kv == 0) {
      bf16x4 v;
#pragma unroll
      for (int r = 0; r < 4; ++r) v[r] = (bf16_t)s[r];
      *(bf16x4*)(Kp + (size_t)bh * 16384 + e4 * 4) = v;
    } else {
      int lk = (e4 * 4) >> 6, hd = (e4 * 4) & 63;
      bf16_t* d = VpT + (size_t)bh * 16384 + lk;
#pragma unroll
      for (int r = 0; r < 4; ++r) d[(size_t)(hd + r) * 256] = (bf16_t)s[r];
    }
  }
}

// ---------------- fused attention: scores -> softmax -> PV ----------------
// Grid (S/64, B*H), 256 threads (4 waves x 16 Q-rows each).
// LDS reused 3x: Kp ([256][64] 128B-row swizzled) -> P (xor) -> Vp ([64][256] swizzled).
__global__ __launch_bounds__(256) void attn_kernel(
    const bf16_t* __restrict__ Q, const bf16_t* __restrict__ Kp, const bf16_t* __restrict__ VpT,
    bf16_t* __restrict__ Xo) {
  int tid = threadIdx.x, lane = tid & 63, wv = tid >> 6;
  int q = lane >> 4, m_in = lane & 15;
  int s0 = blockIdx.x * 64;
  int bh = blockIdx.y;
  int b = bh >> 4, h = bh & 15;
  const bf16_t* Qb = Q + ((size_t)bh * 4096 + s0 + wv * 16) * 64;
  const bf16_t* Kpb = Kp + (size_t)bh * 16384;
  const bf16_t* Vb = VpT + (size_t)bh * 16384;
  __shared__ __align__(16) bf16_t buf[16384];  // 32KB, reused Kp -> P -> Vp

  // stage Kp [256][64]: 128B rows, chunk cc holds source chunk cc^(row&7)
#pragma unroll
  for (int it = 0; it < 8; ++it) {
    int l = it * 256 + tid;
    int row = l >> 3, cc = (l & 7) ^ (row & 7);
    const bf16_t* g = Kpb + row * 64 + cc * 8;
    __builtin_amdgcn_global_load_lds(TO_GLB(g), TO_LDS(buf + (it * 256 + wv * 64) * 8), 16, 0, 0);
  }
  bf16x8 aq[2];
#pragma unroll
  for (int ks = 0; ks < 2; ++ks) aq[ks] = *(const bf16x8*)(Qb + (size_t)m_in * 64 + ks * 32 + q * 8);
  __syncthreads();  // B0: Kp staged

  f32x4 sc[16];
  f32x4 z = {0.f, 0.f, 0.f, 0.f};
#pragma unroll
  for (int nt = 0; nt < 16; ++nt) sc[nt] = z;
#pragma unroll
  for (int nt = 0; nt < 16; ++nt)
#pragma unroll
    for (int ks = 0; ks < 2; ++ks) {
      int nb = nt * 16 + m_in, qq = ks * 4 + q;
      bf16x8 kb = *(const bf16x8*)(buf + nb * 64 + ((qq ^ (nb & 7)) * 8));
      sc[nt] = __builtin_amdgcn_mfma_f32_16x16x32_bf16(aq[ks], kb, sc[nt], 0, 0, 0);
    }

  float mx[4], sm[4];
#pragma unroll
  for (int r = 0; r < 4; ++r) mx[r] = -1e30f;
#pragma unroll
  for (int nt = 0; nt < 16; ++nt)
#pragma unroll
    for (int r = 0; r < 4; ++r) {
      float t = sc[nt][r] * 0.125f;  // 1/sqrt(HD)
      sc[nt][r] = t;
      mx[r] = fmaxf(mx[r], t);
    }
#pragma unroll
  for (int off = 1; off < 16; off <<= 1)
#pragma unroll
    for (int r = 0; r < 4; ++r) mx[r] = fmaxf(mx[r], __shfl_xor(mx[r], off));
#pragma unroll
  for (int r = 0; r < 4; ++r) sm[r] = 0.f;
#pragma unroll
  for (int nt = 0; nt < 16; ++nt)
#pragma unroll
    for (int r = 0; r < 4; ++r) {
      float e = __expf(sc[nt][r] - mx[r]);
      sc[nt][r] = e;
      sm[r] += e;
    }
#pragma unroll
  for (int off = 1; off < 16; off <<= 1)
#pragma unroll
    for (int r = 0; r < 4; ++r) sm[r] += __shfl_xor(sm[r], off);
  float inv[4];
#pragma unroll
  for (int r = 0; r < 4; ++r) inv[r] = 1.0f / sm[r];

  __syncthreads();  // B1: all waves done reading Kp

  bf16_t* Pw = buf + wv * 4096;
#pragma unroll
  for (int nt = 0; nt < 16; ++nt) {
    int cw = nt * 2 + (m_in >> 3);
#pragma unroll
    for (int r = 0; r < 4; ++r) {
      int rp = q * 4 + r;
      int sw = (((cw ^ (rp & 7)) << 3) | (m_in & 7));
      Pw[rp * 256 + sw] = (bf16_t)(sc[nt][r] * inv[r]);
    }
  }
  bf16x8 pa[8];
#pragma unroll
  for (int ks = 0; ks < 8; ++ks) {
    int c = ks * 4 + q;
    pa[ks] = *(const bf16x8*)(Pw + m_in * 256 + ((c ^ (m_in & 7)) << 3));
  }
  __syncthreads();  // B2: all waves hold pa

  // stage Vp [64][256]: 512B rows; position cc holds source chunk with low3 ^= row&7
#pragma unroll
  for (int it = 0; it < 8; ++it) {
    int l = it * 256 + tid;
    int row = l >> 5, cc = l & 31;
    int src_cc = (cc & 24) | ((cc ^ row) & 7);
    const bf16_t* g = Vb + row * 256 + src_cc * 8;
    __builtin_amdgcn_global_load_lds(TO_GLB(g), TO_LDS(buf + (it * 256 + wv * 64) * 8), 16, 0, 0);
  }
  __syncthreads();  // B3: Vp staged

  f32x4 o[4];
#pragma unroll
  for (int nt = 0; nt < 4; ++nt) o[nt] = z;
#pragma unroll
  for (int nt = 0; nt < 4; ++nt)
#pragma unroll
    for (int ks = 0; ks < 8; ++ks) {
      int nb = nt * 16 + m_in, qq = ks * 4 + q;
      int p = (qq & 24) | ((qq ^ nb) & 7);
      bf16x8 vb = *(const bf16x8*)(buf + nb * 256 + p * 8);
      o[nt] = __builtin_amdgcn_mfma_f32_16x16x32_bf16(pa[ks], vb, o[nt], 0, 0, 0);
    }

#pragma unroll
  for (int nt = 0; nt < 4; ++nt)
#pragma unroll
    for (int r = 0; r < 4; ++r)
      Xo[((size_t)b * 4096 + s0 + wv * 16 + q * 4 + r) * 1024 + h * 64 + nt * 16 + m_in] =
          (bf16_t)o[nt][r];
}

extern "C" void kernel_launch(void* const* d_in, const int* in_sizes, int n_in,
                              void* d_out, int out_size, void* d_ws, size_t ws_size,
                              hipStream_t stream) {
  const float* X = (const float*)d_in[0];
  const float* mask = (const float*)d_in[1];
  const float* Wq = (const float*)d_in[2];
  const float* bq = (const float*)d_in[3];
  const float* Wk = (const float*)d_in[4];
  const float* bk = (const float*)d_in[5];
  const float* Wv = (const float*)d_in[6];
  const float* bv = (const float*)d_in[7];
  const float* E = (const float*)d_in[8];
  const float* Wo = (const float*)d_in[9];
  const float* bo = (const float*)d_in[10];
  float* out = (float*)d_out;

  char* ws = (char*)d_ws;
  const size_t SZ = 33554432;  // 32 MB
  bf16_t* Xb = (bf16_t*)(ws);                 // Xb -> gemm2 partials (fp32) -> Xo
  float* Pp = (float*)(ws);                   // 32 MB fp32 partials (alias, Xb dead then)
  bf16_t* Eb = (bf16_t*)(ws + SZ);
  bf16_t* Qb = (bf16_t*)(ws + 2 * SZ);
  bf16_t* KT = (bf16_t*)(ws + 3 * SZ);        // (B,H,HD,S) masked
  bf16_t* VT = (bf16_t*)(ws + 4 * SZ);        // (B,H,HD,S) masked
  bf16_t* Kp = (bf16_t*)(ws + 5 * SZ);                 // (B,H,LK,HD)
  bf16_t* VpT = (bf16_t*)(ws + 5 * SZ + 8388608);      // (B,H,HD,LK)
  bf16_t* WqkvT = (bf16_t*)(ws + 5 * SZ + 2 * 8388608);           // (3072,1024)
  bf16_t* WoT = (bf16_t*)(ws + 5 * SZ + 2 * 8388608 + 6291456);   // (1024,1024)
  bf16_t* Xo = Xb;

  cast2_bf16_kernel<<<32768, 256, 0, stream>>>(X, Xb, E, Eb, 4194304);
  transpose_cast4<<<dim3(16, 16, 4), 256, 0, stream>>>(
      Wq, Wk, Wv, Wo, WqkvT, WqkvT + 1048576, WqkvT + 2097152, WoT);

  gemm_bt_256<<<dim3(64, 24), 512, 0, stream>>>(Xb, WqkvT, 1024, 0, bq, bk, bv, mask,
                                                Qb, KT, VT, nullptr, nullptr);
  gemm2_kernel<<<dim3(2, 64, 8), 512, 0, stream>>>(Eb, KT, VT, Pp);
  gemm2_reduce<<<dim3(64, 2), 256, 0, stream>>>(Pp, Kp, VpT);
  attn_kernel<<<dim3(64, 64), 256, 0, stream>>>(Qb, Kp, VpT, Xo);
  gemm_bt_256<<<dim3(64, 8), 512, 0, stream>>>(Xo, WoT, 1024, 1, nullptr, nullptr, nullptr,
                                               nullptr, nullptr, nullptr, nullptr, bo, out);
}